// Round 1
// baseline (468.842 us; speedup 1.0000x reference)
//
#include <hip/hip_runtime.h>
#include <hip/hip_bf16.h>

typedef __bf16 bf16;
typedef __bf16 bf16x4 __attribute__((ext_vector_type(4)));
typedef __bf16 bf16x8 __attribute__((ext_vector_type(8)));
typedef float f32x4 __attribute__((ext_vector_type(4)));

constexpr int TKN  = 2048;   // tokens
constexpr int HD   = 1024;   // hidden
constexpr int NEXP = 16;     // experts
constexpr int KSEL = 4;      // top-k
constexpr int CAP  = 2048;   // per-expert token capacity
constexpr int IDIM = 1024;   // I
constexpr int I2   = 2048;   // 2*I

// async global->LDS, 16B per lane. LDS dest must be wave-uniform base;
// HW writes lane l at base + l*16.
__device__ __forceinline__ void async_copy16(const void* g, void* l) {
  __builtin_amdgcn_global_load_lds((__attribute__((address_space(1))) void*)g,
                                   (__attribute__((address_space(3))) void*)l,
                                   16, 0, 0);
}

// ---------------- Kernel 1: RMSNorm + gate (fp32) + top-4 + scatter ----------
__global__ __launch_bounds__(256) void k_norm_gate(
    const float* __restrict__ x, const float* __restrict__ scale,
    const float* __restrict__ gate_w, const float* __restrict__ gate_b,
    float* __restrict__ out, bf16* __restrict__ tN,
    int* __restrict__ cnt, int* __restrict__ tokList, float* __restrict__ wList)
{
  __shared__ float tLds[HD];
  __shared__ float red[4];
  __shared__ float gsh[NEXP];
  const int tid = threadIdx.x;
  const int tok = blockIdx.x;
  const int wid = tid >> 6, lane = tid & 63;

  const float4 x4 = *(const float4*)(x + (size_t)tok * HD + tid * 4);
  float ss = x4.x * x4.x + x4.y * x4.y + x4.z * x4.z + x4.w * x4.w;
  #pragma unroll
  for (int off = 32; off > 0; off >>= 1) ss += __shfl_down(ss, off);
  if (lane == 0) red[wid] = ss;
  __syncthreads();
  ss = red[0] + red[1] + red[2] + red[3];
  const float r = rsqrtf(ss * (1.0f / HD) + 1e-5f);

  const float4 s4 = *(const float4*)(scale + tid * 4);
  float4 t4;
  t4.x = x4.x * r * s4.x; t4.y = x4.y * r * s4.y;
  t4.z = x4.z * r * s4.z; t4.w = x4.w * r * s4.w;
  // residual init: out = x
  *(float4*)(out + (size_t)tok * HD + tid * 4) = x4;
  tLds[tid * 4 + 0] = t4.x; tLds[tid * 4 + 1] = t4.y;
  tLds[tid * 4 + 2] = t4.z; tLds[tid * 4 + 3] = t4.w;
  bf16x4 tb;
  tb[0] = (bf16)t4.x; tb[1] = (bf16)t4.y; tb[2] = (bf16)t4.z; tb[3] = (bf16)t4.w;
  *(bf16x4*)(tN + (size_t)tok * HD + tid * 4) = tb;
  __syncthreads();

  // gate logits in fp32 (routing decisions must match fp32 reference)
  {
    const int e = tid >> 4, l16 = tid & 15;
    float p = 0.f;
    const float* gw = gate_w + (size_t)e * HD;
    for (int j = l16; j < HD; j += 16) p += tLds[j] * gw[j];
    p += __shfl_xor(p, 8); p += __shfl_xor(p, 4);
    p += __shfl_xor(p, 2); p += __shfl_xor(p, 1);
    if (l16 == 0) gsh[e] = p + gate_b[e];
  }
  __syncthreads();

  if (tid == 0) {
    float g[NEXP];
    #pragma unroll
    for (int i = 0; i < NEXP; ++i) g[i] = gsh[i];
    int   bi[KSEL]; float bv[KSEL];
    #pragma unroll
    for (int k = 0; k < KSEL; ++k) {
      float best = -1e30f; int b = 0;
      for (int i = 0; i < NEXP; ++i) if (g[i] > best) { best = g[i]; b = i; }
      bv[k] = best; bi[k] = b; g[b] = -1e30f;
    }
    const float m = bv[0];
    float wv[KSEL], sum = 0.f;
    #pragma unroll
    for (int k = 0; k < KSEL; ++k) { wv[k] = __expf(bv[k] - m); sum += wv[k]; }
    const float inv = 1.0f / sum;
    #pragma unroll
    for (int k = 0; k < KSEL; ++k) {
      const int ex = bi[k];
      const int slot = atomicAdd(&cnt[ex], 1);
      tokList[ex * CAP + slot] = tok;
      wList[ex * CAP + slot]   = wv[k] * inv;
    }
  }
}

// ---------------- Kernel 2: 16-wide exclusive scan ---------------------------
__global__ void k_scan(const int* __restrict__ cnt, int* __restrict__ segOff) {
  if (threadIdx.x == 0 && blockIdx.x == 0) {
    int s = 0;
    for (int e = 0; e < NEXP; ++e) { segOff[e] = s; s += cnt[e]; }
  }
}

// ---------------- Kernel 3: grouped GEMM1 (even cols only) + SwiGLU ----------
// C[m,n] = sum_k t[tok(m),k] * w1[e][2n][k] + b1[e][2n]; s = swiglu -> sBuf
__global__ __launch_bounds__(256) void k_gemm1(
    const bf16* __restrict__ tN, const float* __restrict__ w1,
    const float* __restrict__ b1, const int* __restrict__ cnt,
    const int* __restrict__ segOff, const int* __restrict__ tokList,
    bf16* __restrict__ sBuf)
{
  const int e = blockIdx.z, mt = blockIdx.y, nt = blockIdx.x;
  const int rows = cnt[e];
  if (mt * 128 >= rows) return;
  const int soff = segOff[e];
  __shared__ __align__(16) bf16 Asm[128 * 32];
  __shared__ __align__(16) bf16 Bsm[128 * 32];
  const int tid = threadIdx.x;
  const int wid = tid >> 6, lane = tid & 63;
  const int quad = lane >> 4, l16 = lane & 15;
  const int wm = wid & 1, wn = wid >> 1;

  // A staging: 2 rounds x 4 waves x 64 lanes x 16B = 128 rows x 64B
  const int r0 = wid * 16 + (lane >> 2);
  const int r1 = 64 + r0;
  const int colE = (lane & 3) * 8;
  const int m0 = min(mt * 128 + r0, rows - 1);
  const int m1 = min(mt * 128 + r1, rows - 1);
  const char* gA0 = (const char*)(tN + (size_t)tokList[e * CAP + m0] * HD + colE);
  const char* gA1 = (const char*)(tN + (size_t)tokList[e * CAP + m1] * HD + colE);
  bf16* lA0 = Asm + wid * 512;          // wave-uniform LDS base (1KB/wave)
  bf16* lA1 = Asm + 2048 + wid * 512;

  // B staging: fp32 load + cvt + ds_write, 4 rounds of 32 rows
  const int brow = tid >> 3;
  const int bkk  = (tid & 7) * 4;
  const int n0 = nt * 128;
  const float* gB = w1 + (size_t)e * I2 * HD + (size_t)(2 * (n0 + brow)) * HD + bkk;

  const f32x4 zero = {0.f, 0.f, 0.f, 0.f};
  f32x4 acc[4][4];
  #pragma unroll
  for (int i = 0; i < 4; ++i)
    #pragma unroll
    for (int j = 0; j < 4; ++j) acc[i][j] = zero;

  for (int kt = 0; kt < 32; ++kt) {
    async_copy16(gA0, lA0);
    async_copy16(gA1, lA1);
    gA0 += 64; gA1 += 64;
    #pragma unroll
    for (int q = 0; q < 4; ++q) {
      const float4 v = *(const float4*)(gB + (size_t)q * 64 * HD); // +32 even rows
      bf16x4 c;
      c[0] = (bf16)v.x; c[1] = (bf16)v.y; c[2] = (bf16)v.z; c[3] = (bf16)v.w;
      *(bf16x4*)(Bsm + (q * 32 + brow) * 32 + bkk) = c;
    }
    gB += 32;
    __syncthreads();
    bf16x8 av[4], bv[4];
    #pragma unroll
    for (int i = 0; i < 4; ++i)
      av[i] = *(const bf16x8*)(Asm + (wm * 64 + i * 16 + l16) * 32 + quad * 8);
    #pragma unroll
    for (int j = 0; j < 4; ++j)
      bv[j] = *(const bf16x8*)(Bsm + (wn * 64 + j * 16 + l16) * 32 + quad * 8);
    #pragma unroll
    for (int i = 0; i < 4; ++i)
      #pragma unroll
      for (int j = 0; j < 4; ++j)
        acc[i][j] = __builtin_amdgcn_mfma_f32_16x16x32_bf16(av[i], bv[j], acc[i][j], 0, 0, 0);
    __syncthreads();
  }

  // epilogue: bias + swiglu (odd-col term is the constant 8.0 -- source bug)
  const int mbase = mt * 128 + wm * 64;
  #pragma unroll
  for (int j = 0; j < 4; ++j) {
    const int ncol = n0 + wn * 64 + j * 16 + l16;
    const float bias = b1[(size_t)e * I2 + 2 * ncol];
    #pragma unroll
    for (int i = 0; i < 4; ++i) {
      #pragma unroll
      for (int rg = 0; rg < 4; ++rg) {
        const int gm = mbase + i * 16 + quad * 4 + rg;
        if (gm < rows) {
          const float h  = acc[i][j][rg] + bias;
          const float xg = fminf(h, 7.0f);
          const float s  = xg * (1.0f / (1.0f + __expf(-1.702f * xg))) * 8.0f;
          sBuf[((size_t)soff + gm) * IDIM + ncol] = (bf16)s;
        }
      }
    }
  }
}

// ---------------- Kernel 4: grouped GEMM2 + bias + weighted scatter-add ------
// y[m,h] = sum_i s[m,i] * w2[e][h][i] + b2[e][h]; out[tok] += w * y
__global__ __launch_bounds__(256) void k_gemm2(
    const bf16* __restrict__ sBuf, const float* __restrict__ w2,
    const float* __restrict__ b2, const int* __restrict__ cnt,
    const int* __restrict__ segOff, const int* __restrict__ tokList,
    const float* __restrict__ wList, float* __restrict__ out)
{
  const int e = blockIdx.z, mt = blockIdx.y, nt = blockIdx.x;
  const int rows = cnt[e];
  if (mt * 128 >= rows) return;
  const int soff = segOff[e];
  __shared__ __align__(16) bf16 Asm[128 * 32];
  __shared__ __align__(16) bf16 Bsm[128 * 32];
  const int tid = threadIdx.x;
  const int wid = tid >> 6, lane = tid & 63;
  const int quad = lane >> 4, l16 = lane & 15;
  const int wm = wid & 1, wn = wid >> 1;

  const int r0 = wid * 16 + (lane >> 2);
  const int r1 = 64 + r0;
  const int colE = (lane & 3) * 8;
  const int m0 = min(mt * 128 + r0, rows - 1);
  const int m1 = min(mt * 128 + r1, rows - 1);
  const char* gA0 = (const char*)(sBuf + ((size_t)soff + m0) * IDIM + colE);
  const char* gA1 = (const char*)(sBuf + ((size_t)soff + m1) * IDIM + colE);
  bf16* lA0 = Asm + wid * 512;
  bf16* lA1 = Asm + 2048 + wid * 512;

  const int brow = tid >> 3;
  const int bkk  = (tid & 7) * 4;
  const int n0 = nt * 128;
  const float* gB = w2 + (size_t)e * HD * IDIM + (size_t)(n0 + brow) * IDIM + bkk;

  const f32x4 zero = {0.f, 0.f, 0.f, 0.f};
  f32x4 acc[4][4];
  #pragma unroll
  for (int i = 0; i < 4; ++i)
    #pragma unroll
    for (int j = 0; j < 4; ++j) acc[i][j] = zero;

  for (int kt = 0; kt < 32; ++kt) {
    async_copy16(gA0, lA0);
    async_copy16(gA1, lA1);
    gA0 += 64; gA1 += 64;
    #pragma unroll
    for (int q = 0; q < 4; ++q) {
      const float4 v = *(const float4*)(gB + (size_t)q * 32 * IDIM);
      bf16x4 c;
      c[0] = (bf16)v.x; c[1] = (bf16)v.y; c[2] = (bf16)v.z; c[3] = (bf16)v.w;
      *(bf16x4*)(Bsm + (q * 32 + brow) * 32 + bkk) = c;
    }
    gB += 32;
    __syncthreads();
    bf16x8 av[4], bv[4];
    #pragma unroll
    for (int i = 0; i < 4; ++i)
      av[i] = *(const bf16x8*)(Asm + (wm * 64 + i * 16 + l16) * 32 + quad * 8);
    #pragma unroll
    for (int j = 0; j < 4; ++j)
      bv[j] = *(const bf16x8*)(Bsm + (wn * 64 + j * 16 + l16) * 32 + quad * 8);
    #pragma unroll
    for (int i = 0; i < 4; ++i)
      #pragma unroll
      for (int j = 0; j < 4; ++j)
        acc[i][j] = __builtin_amdgcn_mfma_f32_16x16x32_bf16(av[i], bv[j], acc[i][j], 0, 0, 0);
    __syncthreads();
  }

  const int mbase = mt * 128 + wm * 64;
  #pragma unroll
  for (int j = 0; j < 4; ++j) {
    const int ncol = n0 + wn * 64 + j * 16 + l16;
    const float bias = b2[(size_t)e * HD + ncol];
    #pragma unroll
    for (int i = 0; i < 4; ++i) {
      #pragma unroll
      for (int rg = 0; rg < 4; ++rg) {
        const int gm = mbase + i * 16 + quad * 4 + rg;
        if (gm < rows) {
          const int   tok = tokList[e * CAP + gm];
          const float wgt = wList[e * CAP + gm];
          atomicAdd(out + (size_t)tok * HD + ncol, wgt * (acc[i][j][rg] + bias));
        }
      }
    }
  }
}

// ---------------- launch -----------------------------------------------------
extern "C" void kernel_launch(void* const* d_in, const int* in_sizes, int n_in,
                              void* d_out, int out_size, void* d_ws, size_t ws_size,
                              hipStream_t stream) {
  const float* x      = (const float*)d_in[0];
  const float* scale  = (const float*)d_in[1];
  const float* gate_w = (const float*)d_in[2];
  const float* gate_b = (const float*)d_in[3];
  const float* w1     = (const float*)d_in[4];
  const float* b1     = (const float*)d_in[5];
  const float* w2     = (const float*)d_in[6];
  const float* b2     = (const float*)d_in[7];
  float* out = (float*)d_out;

  char* p = (char*)d_ws;
  bf16* tN = (bf16*)p;        p += (size_t)TKN * HD * 2;          // 4 MB
  bf16* sBuf = (bf16*)p;      p += (size_t)(TKN * KSEL) * IDIM * 2; // 16 MB
  int* cnt = (int*)p;         p += 256;
  int* segOff = (int*)p;      p += 256;
  int* tokList = (int*)p;     p += (size_t)NEXP * CAP * 4;        // 128 KB
  float* wList = (float*)p;   p += (size_t)NEXP * CAP * 4;        // 128 KB

  hipMemsetAsync(cnt, 0, 256, stream);
  k_norm_gate<<<TKN, 256, 0, stream>>>(x, scale, gate_w, gate_b, out, tN,
                                       cnt, tokList, wList);
  k_scan<<<1, 64, 0, stream>>>(cnt, segOff);
  k_gemm1<<<dim3(8, 16, NEXP), 256, 0, stream>>>(tN, w1, b1, cnt, segOff,
                                                 tokList, sBuf);
  k_gemm2<<<dim3(8, 16, NEXP), 256, 0, stream>>>(sBuf, w2, b2, cnt, segOff,
                                                 tokList, wList, out);
}

// Round 3
// 395.794 us; speedup vs baseline: 1.1846x; 1.1846x over previous
//
#include <hip/hip_runtime.h>
#include <hip/hip_bf16.h>

typedef __bf16 bf16;
typedef __bf16 bf16x4 __attribute__((ext_vector_type(4)));
typedef __bf16 bf16x8 __attribute__((ext_vector_type(8)));
typedef float f32x4 __attribute__((ext_vector_type(4)));

constexpr int TKN  = 2048;   // tokens
constexpr int HD   = 1024;   // hidden
constexpr int NEXP = 16;     // experts
constexpr int KSEL = 4;      // top-k
constexpr int IDIM = 1024;   // I
constexpr int I2   = 2048;   // 2*I
constexpr int NROW = TKN * KSEL;  // 8192 token-expert rows

// async global->LDS, 16B per lane; lane l lands at base + l*16 (wave-uniform base).
__device__ __forceinline__ void async_copy16(const void* g, void* l) {
  __builtin_amdgcn_global_load_lds((__attribute__((address_space(1))) void*)g,
                                   (__attribute__((address_space(3))) void*)l,
                                   16, 0, 0);
}

// ------ Kernel 1: RMSNorm + fp32 gate + top-4 (NO global atomics) + out=x ----
__global__ __launch_bounds__(256) void k_norm_gate(
    const float* __restrict__ x, const float* __restrict__ scale,
    const float* __restrict__ gate_w, const float* __restrict__ gate_b,
    float* __restrict__ out, bf16* __restrict__ tN,
    int* __restrict__ eids, float* __restrict__ wts)
{
  __shared__ float tLds[HD];
  __shared__ float red[4];
  __shared__ float gsh[NEXP];
  const int tid = threadIdx.x;
  const int tok = blockIdx.x;
  const int wid = tid >> 6, lane = tid & 63;

  const float4 x4 = *(const float4*)(x + (size_t)tok * HD + tid * 4);
  float ss = x4.x * x4.x + x4.y * x4.y + x4.z * x4.z + x4.w * x4.w;
  #pragma unroll
  for (int off = 32; off > 0; off >>= 1) ss += __shfl_down(ss, off);
  if (lane == 0) red[wid] = ss;
  __syncthreads();
  ss = red[0] + red[1] + red[2] + red[3];
  const float r = rsqrtf(ss * (1.0f / HD) + 1e-5f);

  const float4 s4 = *(const float4*)(scale + tid * 4);
  float4 t4;
  t4.x = x4.x * r * s4.x; t4.y = x4.y * r * s4.y;
  t4.z = x4.z * r * s4.z; t4.w = x4.w * r * s4.w;
  // residual init: out = x
  *(float4*)(out + (size_t)tok * HD + tid * 4) = x4;
  tLds[tid * 4 + 0] = t4.x; tLds[tid * 4 + 1] = t4.y;
  tLds[tid * 4 + 2] = t4.z; tLds[tid * 4 + 3] = t4.w;
  bf16x4 tb;
  tb[0] = (bf16)t4.x; tb[1] = (bf16)t4.y; tb[2] = (bf16)t4.z; tb[3] = (bf16)t4.w;
  *(bf16x4*)(tN + (size_t)tok * HD + tid * 4) = tb;
  __syncthreads();

  // gate logits in fp32 (routing decisions must match fp32 reference)
  {
    const int e = tid >> 4, l16 = tid & 15;
    float p = 0.f;
    const float* gw = gate_w + (size_t)e * HD;
    for (int j = l16; j < HD; j += 16) p += tLds[j] * gw[j];
    p += __shfl_xor(p, 8); p += __shfl_xor(p, 4);
    p += __shfl_xor(p, 2); p += __shfl_xor(p, 1);
    if (l16 == 0) gsh[e] = p + gate_b[e];
  }
  __syncthreads();

  if (tid == 0) {
    float g[NEXP];
    #pragma unroll
    for (int i = 0; i < NEXP; ++i) g[i] = gsh[i];
    int   bi[KSEL]; float bv[KSEL];
    #pragma unroll
    for (int k = 0; k < KSEL; ++k) {
      float best = -1e30f; int b = 0;
      for (int i = 0; i < NEXP; ++i) if (g[i] > best) { best = g[i]; b = i; }
      bv[k] = best; bi[k] = b; g[b] = -1e30f;
    }
    const float m = bv[0];
    float wv[KSEL], sum = 0.f;
    #pragma unroll
    for (int k = 0; k < KSEL; ++k) { wv[k] = __expf(bv[k] - m); sum += wv[k]; }
    const float inv = 1.0f / sum;
    #pragma unroll
    for (int k = 0; k < KSEL; ++k) {
      eids[tok * KSEL + k] = bi[k];
      wts[tok * KSEL + k]  = wv[k] * inv;
    }
  }
}

// ------ Kernel 2: bucket build (single block, LDS atomics only) --------------
__global__ __launch_bounds__(256) void k_route(
    const int* __restrict__ eids, const float* __restrict__ wts,
    int* __restrict__ cntg, int* __restrict__ segg,
    int* __restrict__ rowTok, float* __restrict__ rowW)
{
  __shared__ int hcnt[NEXP], hoff[NEXP], hrun[NEXP];
  const int tid = threadIdx.x;
  if (tid < NEXP) { hcnt[tid] = 0; hrun[tid] = 0; }
  __syncthreads();
  for (int i = tid; i < NROW; i += 256) atomicAdd(&hcnt[eids[i]], 1);
  __syncthreads();
  if (tid == 0) {
    int s = 0;
    for (int e = 0; e < NEXP; ++e) { hoff[e] = s; segg[e] = s; cntg[e] = hcnt[e]; s += hcnt[e]; }
  }
  __syncthreads();
  for (int i = tid; i < NROW; i += 256) {
    const int e = eids[i];
    const int slot = atomicAdd(&hrun[e], 1);
    const int row = hoff[e] + slot;
    rowTok[row] = i >> 2;          // token index
    rowW[row]   = wts[i];          // routing weight for this row
  }
}

// ------ Kernel 3: grouped GEMM1 (even cols only) + SwiGLU --------------------
// C[m,n] = sum_k t[tok(m),k] * w1[e][2n][k] + b1[e][2n]; s = swiglu -> sBuf
__global__ __launch_bounds__(256) void k_gemm1(
    const bf16* __restrict__ tN, const float* __restrict__ w1,
    const float* __restrict__ b1, const int* __restrict__ cnt,
    const int* __restrict__ segOff, const int* __restrict__ rowTok,
    bf16* __restrict__ sBuf)
{
  const int e = blockIdx.z, mt = blockIdx.y, nt = blockIdx.x;
  const int rows = cnt[e];
  if (mt * 128 >= rows) return;
  const int soff = segOff[e];
  __shared__ __align__(16) bf16 Asm[128 * 32];
  __shared__ __align__(16) bf16 Bsm[128 * 32];
  const int tid = threadIdx.x;
  const int wid = tid >> 6, lane = tid & 63;
  const int quad = lane >> 4, l16 = lane & 15;
  const int wm = wid & 1, wn = wid >> 1;

  // A staging: 2 rounds x 4 waves x 64 lanes x 16B = 128 rows x 64B
  const int r0 = wid * 16 + (lane >> 2);
  const int r1 = 64 + r0;
  const int colE = (lane & 3) * 8;
  const int m0 = min(mt * 128 + r0, rows - 1);
  const int m1 = min(mt * 128 + r1, rows - 1);
  const char* gA0 = (const char*)(tN + (size_t)rowTok[soff + m0] * HD + colE);
  const char* gA1 = (const char*)(tN + (size_t)rowTok[soff + m1] * HD + colE);
  bf16* lA0 = Asm + wid * 512;          // wave-uniform LDS base (1KB/wave)
  bf16* lA1 = Asm + 2048 + wid * 512;

  // B staging: fp32 load + cvt + ds_write, 4 rounds of 32 rows
  const int brow = tid >> 3;
  const int bkk  = (tid & 7) * 4;
  const int n0 = nt * 128;
  const float* gB = w1 + (size_t)e * I2 * HD + (size_t)(2 * (n0 + brow)) * HD + bkk;

  const f32x4 zero = {0.f, 0.f, 0.f, 0.f};
  f32x4 acc[4][4];
  #pragma unroll
  for (int i = 0; i < 4; ++i)
    #pragma unroll
    for (int j = 0; j < 4; ++j) acc[i][j] = zero;

  for (int kt = 0; kt < 32; ++kt) {
    async_copy16(gA0, lA0);
    async_copy16(gA1, lA1);
    gA0 += 64; gA1 += 64;
    #pragma unroll
    for (int q = 0; q < 4; ++q) {
      const float4 v = *(const float4*)(gB + (size_t)q * 64 * HD); // +32 even rows
      bf16x4 c;
      c[0] = (bf16)v.x; c[1] = (bf16)v.y; c[2] = (bf16)v.z; c[3] = (bf16)v.w;
      *(bf16x4*)(Bsm + (q * 32 + brow) * 32 + bkk) = c;
    }
    gB += 32;
    __syncthreads();
    bf16x8 av[4], bv[4];
    #pragma unroll
    for (int i = 0; i < 4; ++i)
      av[i] = *(const bf16x8*)(Asm + (wm * 64 + i * 16 + l16) * 32 + quad * 8);
    #pragma unroll
    for (int j = 0; j < 4; ++j)
      bv[j] = *(const bf16x8*)(Bsm + (wn * 64 + j * 16 + l16) * 32 + quad * 8);
    #pragma unroll
    for (int i = 0; i < 4; ++i)
      #pragma unroll
      for (int j = 0; j < 4; ++j)
        acc[i][j] = __builtin_amdgcn_mfma_f32_16x16x32_bf16(av[i], bv[j], acc[i][j], 0, 0, 0);
    __syncthreads();
  }

  // epilogue: bias + swiglu (odd-col term is the constant 8.0 -- source bug)
  const int mbase = mt * 128 + wm * 64;
  #pragma unroll
  for (int j = 0; j < 4; ++j) {
    const int ncol = n0 + wn * 64 + j * 16 + l16;
    const float bias = b1[(size_t)e * I2 + 2 * ncol];
    #pragma unroll
    for (int i = 0; i < 4; ++i) {
      #pragma unroll
      for (int rg = 0; rg < 4; ++rg) {
        const int gm = mbase + i * 16 + quad * 4 + rg;
        if (gm < rows) {
          const float h  = acc[i][j][rg] + bias;
          const float xg = fminf(h, 7.0f);
          const float s  = xg * (1.0f / (1.0f + __expf(-1.702f * xg))) * 8.0f;
          sBuf[((size_t)soff + gm) * IDIM + ncol] = (bf16)s;
        }
      }
    }
  }
}

// ------ Kernel 4: grouped GEMM2 + bias + weighted atomic scatter-add ---------
// y[m,h] = sum_i s[m,i] * w2[e][h][i] + b2[e][h]; out[tok] += w * y
__global__ __launch_bounds__(256) void k_gemm2(
    const bf16* __restrict__ sBuf, const float* __restrict__ w2,
    const float* __restrict__ b2, const int* __restrict__ cnt,
    const int* __restrict__ segOff, const int* __restrict__ rowTok,
    const float* __restrict__ rowW, float* __restrict__ out)
{
  const int e = blockIdx.z, mt = blockIdx.y, nt = blockIdx.x;
  const int rows = cnt[e];
  if (mt * 128 >= rows) return;
  const int soff = segOff[e];
  __shared__ __align__(16) bf16 Asm[128 * 32];
  __shared__ __align__(16) bf16 Bsm[128 * 32];
  const int tid = threadIdx.x;
  const int wid = tid >> 6, lane = tid & 63;
  const int quad = lane >> 4, l16 = lane & 15;
  const int wm = wid & 1, wn = wid >> 1;

  const int r0 = wid * 16 + (lane >> 2);
  const int r1 = 64 + r0;
  const int colE = (lane & 3) * 8;
  const int m0 = min(mt * 128 + r0, rows - 1);
  const int m1 = min(mt * 128 + r1, rows - 1);
  const char* gA0 = (const char*)(sBuf + ((size_t)soff + m0) * IDIM + colE);
  const char* gA1 = (const char*)(sBuf + ((size_t)soff + m1) * IDIM + colE);
  bf16* lA0 = Asm + wid * 512;
  bf16* lA1 = Asm + 2048 + wid * 512;

  const int brow = tid >> 3;
  const int bkk  = (tid & 7) * 4;
  const int n0 = nt * 128;
  const float* gB = w2 + (size_t)e * HD * IDIM + (size_t)(n0 + brow) * IDIM + bkk;

  const f32x4 zero = {0.f, 0.f, 0.f, 0.f};
  f32x4 acc[4][4];
  #pragma unroll
  for (int i = 0; i < 4; ++i)
    #pragma unroll
    for (int j = 0; j < 4; ++j) acc[i][j] = zero;

  for (int kt = 0; kt < 32; ++kt) {
    async_copy16(gA0, lA0);
    async_copy16(gA1, lA1);
    gA0 += 64; gA1 += 64;
    #pragma unroll
    for (int q = 0; q < 4; ++q) {
      const float4 v = *(const float4*)(gB + (size_t)q * 32 * IDIM);
      bf16x4 c;
      c[0] = (bf16)v.x; c[1] = (bf16)v.y; c[2] = (bf16)v.z; c[3] = (bf16)v.w;
      *(bf16x4*)(Bsm + (q * 32 + brow) * 32 + bkk) = c;
    }
    gB += 32;
    __syncthreads();
    bf16x8 av[4], bv[4];
    #pragma unroll
    for (int i = 0; i < 4; ++i)
      av[i] = *(const bf16x8*)(Asm + (wm * 64 + i * 16 + l16) * 32 + quad * 8);
    #pragma unroll
    for (int j = 0; j < 4; ++j)
      bv[j] = *(const bf16x8*)(Bsm + (wn * 64 + j * 16 + l16) * 32 + quad * 8);
    #pragma unroll
    for (int i = 0; i < 4; ++i)
      #pragma unroll
      for (int j = 0; j < 4; ++j)
        acc[i][j] = __builtin_amdgcn_mfma_f32_16x16x32_bf16(av[i], bv[j], acc[i][j], 0, 0, 0);
    __syncthreads();
  }

  const int mbase = mt * 128 + wm * 64;
  #pragma unroll
  for (int j = 0; j < 4; ++j) {
    const int ncol = n0 + wn * 64 + j * 16 + l16;
    const float bias = b2[(size_t)e * HD + ncol];
    #pragma unroll
    for (int i = 0; i < 4; ++i) {
      #pragma unroll
      for (int rg = 0; rg < 4; ++rg) {
        const int gm = mbase + i * 16 + quad * 4 + rg;
        if (gm < rows) {
          const int   tok = rowTok[soff + gm];
          const float wgt = rowW[soff + gm];
          atomicAdd(out + (size_t)tok * HD + ncol, wgt * (acc[i][j][rg] + bias));
        }
      }
    }
  }
}

// ---------------- launch -----------------------------------------------------
extern "C" void kernel_launch(void* const* d_in, const int* in_sizes, int n_in,
                              void* d_out, int out_size, void* d_ws, size_t ws_size,
                              hipStream_t stream) {
  const float* x      = (const float*)d_in[0];
  const float* scale  = (const float*)d_in[1];
  const float* gate_w = (const float*)d_in[2];
  const float* gate_b = (const float*)d_in[3];
  const float* w1     = (const float*)d_in[4];
  const float* b1     = (const float*)d_in[5];
  const float* w2     = (const float*)d_in[6];
  const float* b2     = (const float*)d_in[7];
  float* out = (float*)d_out;

  // workspace: 21.1 MB total (round-1's 20.7 MB footprint proved safe)
  char* p = (char*)d_ws;
  bf16* tN   = (bf16*)p;  p += (size_t)TKN * HD * 2;        // 4 MB
  bf16* sBuf = (bf16*)p;  p += (size_t)NROW * IDIM * 2;     // 16 MB
  int*   eids   = (int*)p;   p += (size_t)NROW * 4;         // 32 KB
  float* wts    = (float*)p; p += (size_t)NROW * 4;         // 32 KB
  int*   rowTok = (int*)p;   p += (size_t)NROW * 4;         // 32 KB
  float* rowW   = (float*)p; p += (size_t)NROW * 4;         // 32 KB
  int*   cntg   = (int*)p;   p += 256;
  int*   segg   = (int*)p;   p += 256;

  k_norm_gate<<<TKN, 256, 0, stream>>>(x, scale, gate_w, gate_b, out, tN, eids, wts);
  k_route<<<1, 256, 0, stream>>>(eids, wts, cntg, segg, rowTok, rowW);
  k_gemm1<<<dim3(8, 16, NEXP), 256, 0, stream>>>(tN, w1, b1, cntg, segg, rowTok, sBuf);
  k_gemm2<<<dim3(8, 16, NEXP), 256, 0, stream>>>(sBuf, w2, b2, cntg, segg, rowTok, rowW, out);
}

// Round 4
// 387.850 us; speedup vs baseline: 1.2088x; 1.0205x over previous
//
#include <hip/hip_runtime.h>
#include <hip/hip_bf16.h>

typedef __bf16 bf16;
typedef __bf16 bf16x4 __attribute__((ext_vector_type(4)));
typedef __bf16 bf16x8 __attribute__((ext_vector_type(8)));
typedef float f32x4 __attribute__((ext_vector_type(4)));

constexpr int TKN  = 2048;   // tokens
constexpr int HD   = 1024;   // hidden
constexpr int NEXP = 16;     // experts
constexpr int KSEL = 4;      // top-k
constexpr int IDIM = 1024;   // I
constexpr int I2   = 2048;   // 2*I
constexpr int NROW = TKN * KSEL;  // 8192 token-expert rows

// async global->LDS, 16B per lane; lane l lands at base + l*16 (wave-uniform base).
__device__ __forceinline__ void async_copy16(const void* g, void* l) {
  __builtin_amdgcn_global_load_lds((__attribute__((address_space(1))) void*)g,
                                   (__attribute__((address_space(3))) void*)l,
                                   16, 0, 0);
}

// ------ Kernel 1: RMSNorm + fp32 gate + top-4 (NO global atomics) + out=x ----
__global__ __launch_bounds__(256) void k_norm_gate(
    const float* __restrict__ x, const float* __restrict__ scale,
    const float* __restrict__ gate_w, const float* __restrict__ gate_b,
    float* __restrict__ out, bf16* __restrict__ tN,
    int* __restrict__ eids, float* __restrict__ wts)
{
  __shared__ float tLds[HD];
  __shared__ float red[4];
  __shared__ float gsh[NEXP];
  const int tid = threadIdx.x;
  const int tok = blockIdx.x;
  const int wid = tid >> 6, lane = tid & 63;

  const float4 x4 = *(const float4*)(x + (size_t)tok * HD + tid * 4);
  float ss = x4.x * x4.x + x4.y * x4.y + x4.z * x4.z + x4.w * x4.w;
  #pragma unroll
  for (int off = 32; off > 0; off >>= 1) ss += __shfl_down(ss, off);
  if (lane == 0) red[wid] = ss;
  __syncthreads();
  ss = red[0] + red[1] + red[2] + red[3];
  const float r = rsqrtf(ss * (1.0f / HD) + 1e-5f);

  const float4 s4 = *(const float4*)(scale + tid * 4);
  float4 t4;
  t4.x = x4.x * r * s4.x; t4.y = x4.y * r * s4.y;
  t4.z = x4.z * r * s4.z; t4.w = x4.w * r * s4.w;
  // residual init: out = x
  *(float4*)(out + (size_t)tok * HD + tid * 4) = x4;
  tLds[tid * 4 + 0] = t4.x; tLds[tid * 4 + 1] = t4.y;
  tLds[tid * 4 + 2] = t4.z; tLds[tid * 4 + 3] = t4.w;
  bf16x4 tb;
  tb[0] = (bf16)t4.x; tb[1] = (bf16)t4.y; tb[2] = (bf16)t4.z; tb[3] = (bf16)t4.w;
  *(bf16x4*)(tN + (size_t)tok * HD + tid * 4) = tb;
  __syncthreads();

  // gate logits in fp32 (routing decisions must match fp32 reference)
  {
    const int e = tid >> 4, l16 = tid & 15;
    float p = 0.f;
    const float* gw = gate_w + (size_t)e * HD;
    for (int j = l16; j < HD; j += 16) p += tLds[j] * gw[j];
    p += __shfl_xor(p, 8); p += __shfl_xor(p, 4);
    p += __shfl_xor(p, 2); p += __shfl_xor(p, 1);
    if (l16 == 0) gsh[e] = p + gate_b[e];
  }
  __syncthreads();

  if (tid == 0) {
    float g[NEXP];
    #pragma unroll
    for (int i = 0; i < NEXP; ++i) g[i] = gsh[i];
    int   bi[KSEL]; float bv[KSEL];
    #pragma unroll
    for (int k = 0; k < KSEL; ++k) {
      float best = -1e30f; int b = 0;
      for (int i = 0; i < NEXP; ++i) if (g[i] > best) { best = g[i]; b = i; }
      bv[k] = best; bi[k] = b; g[b] = -1e30f;
    }
    const float m = bv[0];
    float wv[KSEL], sum = 0.f;
    #pragma unroll
    for (int k = 0; k < KSEL; ++k) { wv[k] = __expf(bv[k] - m); sum += wv[k]; }
    const float inv = 1.0f / sum;
    #pragma unroll
    for (int k = 0; k < KSEL; ++k) {
      eids[tok * KSEL + k] = bi[k];
      wts[tok * KSEL + k]  = wv[k] * inv;
    }
  }
}

// ------ Kernel 2: bucket build (single block, LDS atomics only) --------------
__global__ __launch_bounds__(256) void k_route(
    const int* __restrict__ eids, const float* __restrict__ wts,
    int* __restrict__ cntg, int* __restrict__ segg,
    int* __restrict__ rowTok, float* __restrict__ rowW)
{
  __shared__ int hcnt[NEXP], hoff[NEXP], hrun[NEXP];
  const int tid = threadIdx.x;
  if (tid < NEXP) { hcnt[tid] = 0; hrun[tid] = 0; }
  __syncthreads();
  for (int i = tid; i < NROW; i += 256) atomicAdd(&hcnt[eids[i]], 1);
  __syncthreads();
  if (tid == 0) {
    int s = 0;
    for (int e = 0; e < NEXP; ++e) { hoff[e] = s; segg[e] = s; cntg[e] = hcnt[e]; s += hcnt[e]; }
  }
  __syncthreads();
  for (int i = tid; i < NROW; i += 256) {
    const int e = eids[i];
    const int slot = atomicAdd(&hrun[e], 1);
    const int row = hoff[e] + slot;
    rowTok[row] = i >> 2;          // token index
    rowW[row]   = wts[i];          // routing weight for this row
  }
}

// ------ weight conversion fp32 -> bf16 ---------------------------------------
// w1 even rows only: w1b[e][n][k] = w1[e][2n][k]  (odd rows never matter: the
// reference's x_lin = clip(h_odd,7,7) == 7 -> constant factor 8.0)
__global__ __launch_bounds__(256) void k_cvt_w1(const float* __restrict__ w1,
                                                bf16* __restrict__ w1b) {
  const size_t f = (size_t)blockIdx.x * 256 + threadIdx.x;   // 8 elems/thread
  const size_t row = f >> 7;                 // [0, 16*1024)
  const int    off = (int)(f & 127) * 8;
  const size_t e = row >> 10, n = row & 1023;
  const float* s = w1 + (e * 2048 + 2 * n) * 1024 + off;
  const float4 a = *(const float4*)(s);
  const float4 b = *(const float4*)(s + 4);
  bf16x8 o;
  o[0] = (bf16)a.x; o[1] = (bf16)a.y; o[2] = (bf16)a.z; o[3] = (bf16)a.w;
  o[4] = (bf16)b.x; o[5] = (bf16)b.y; o[6] = (bf16)b.z; o[7] = (bf16)b.w;
  *(bf16x8*)(w1b + row * 1024 + off) = o;
}

__global__ __launch_bounds__(256) void k_cvt_w2(const float* __restrict__ w2,
                                                bf16* __restrict__ w2b) {
  const size_t f = (size_t)blockIdx.x * 256 + threadIdx.x;
  const size_t base = f * 8;
  const float4 a = *(const float4*)(w2 + base);
  const float4 b = *(const float4*)(w2 + base + 4);
  bf16x8 o;
  o[0] = (bf16)a.x; o[1] = (bf16)a.y; o[2] = (bf16)a.z; o[3] = (bf16)a.w;
  o[4] = (bf16)b.x; o[5] = (bf16)b.y; o[6] = (bf16)b.z; o[7] = (bf16)b.w;
  *(bf16x8*)(w2b + base) = o;
}

// ------ Kernel 3: grouped GEMM1 (even cols only) + SwiGLU --------------------
// C[m,n] = sum_k t[tok(m),k] * w1[e][2n][k] + b1[e][2n]; s = swiglu -> sBuf
template <bool PREP>
__global__ __launch_bounds__(256) void k_gemm1(
    const bf16* __restrict__ tN, const float* __restrict__ w1,
    const bf16* __restrict__ w1b, const float* __restrict__ b1,
    const int* __restrict__ cnt, const int* __restrict__ segOff,
    const int* __restrict__ rowTok, bf16* __restrict__ sBuf)
{
  const int e = blockIdx.z, mt = blockIdx.y, nt = blockIdx.x;
  const int rows = cnt[e];
  if (mt * 128 >= rows) return;
  const int soff = segOff[e];
  __shared__ __align__(16) bf16 Asm[128 * 32];
  __shared__ __align__(16) bf16 Bsm[128 * 32];
  const int tid = threadIdx.x;
  const int wid = tid >> 6, lane = tid & 63;
  const int quad = lane >> 4, l16 = lane & 15;
  const int wm = wid & 1, wn = wid >> 1;

  // A staging: 2 rounds x 4 waves x 64 lanes x 16B = 128 rows x 64B
  const int r0 = wid * 16 + (lane >> 2);
  const int r1 = 64 + r0;
  const int colE = (lane & 3) * 8;
  const int m0 = min(mt * 128 + r0, rows - 1);
  const int m1 = min(mt * 128 + r1, rows - 1);
  const char* gA0 = (const char*)(tN + (size_t)rowTok[soff + m0] * HD + colE);
  const char* gA1 = (const char*)(tN + (size_t)rowTok[soff + m1] * HD + colE);
  bf16* lA0 = Asm + wid * 512;          // wave-uniform LDS base (1KB/wave)
  bf16* lA1 = Asm + 2048 + wid * 512;

  const int n0 = nt * 128;
  // PREP: bf16 B via async copy, same interleave as A
  const char* gB0 = (const char*)(w1b + (size_t)e * IDIM * HD + (size_t)(n0 + r0) * HD + colE);
  const char* gB1 = (const char*)(w1b + (size_t)e * IDIM * HD + (size_t)(n0 + r1) * HD + colE);
  bf16* lB0 = Bsm + wid * 512;
  bf16* lB1 = Bsm + 2048 + wid * 512;
  // fallback: fp32 load + cvt + ds_write, 4 rounds of 32 rows
  const int brow = tid >> 3;
  const int bkk  = (tid & 7) * 4;
  const float* gB = w1 + (size_t)e * I2 * HD + (size_t)(2 * (n0 + brow)) * HD + bkk;

  const f32x4 zero = {0.f, 0.f, 0.f, 0.f};
  f32x4 acc[4][4];
  #pragma unroll
  for (int i = 0; i < 4; ++i)
    #pragma unroll
    for (int j = 0; j < 4; ++j) acc[i][j] = zero;

  for (int kt = 0; kt < 32; ++kt) {
    async_copy16(gA0, lA0);
    async_copy16(gA1, lA1);
    gA0 += 64; gA1 += 64;
    if constexpr (PREP) {
      async_copy16(gB0, lB0);
      async_copy16(gB1, lB1);
      gB0 += 64; gB1 += 64;
    } else {
      #pragma unroll
      for (int q = 0; q < 4; ++q) {
        const float4 v = *(const float4*)(gB + (size_t)q * 64 * HD); // +32 even rows
        bf16x4 c;
        c[0] = (bf16)v.x; c[1] = (bf16)v.y; c[2] = (bf16)v.z; c[3] = (bf16)v.w;
        *(bf16x4*)(Bsm + (q * 32 + brow) * 32 + bkk) = c;
      }
      gB += 32;
    }
    __syncthreads();
    bf16x8 av[4], bv[4];
    #pragma unroll
    for (int i = 0; i < 4; ++i)
      av[i] = *(const bf16x8*)(Asm + (wm * 64 + i * 16 + l16) * 32 + quad * 8);
    #pragma unroll
    for (int j = 0; j < 4; ++j)
      bv[j] = *(const bf16x8*)(Bsm + (wn * 64 + j * 16 + l16) * 32 + quad * 8);
    #pragma unroll
    for (int i = 0; i < 4; ++i)
      #pragma unroll
      for (int j = 0; j < 4; ++j)
        acc[i][j] = __builtin_amdgcn_mfma_f32_16x16x32_bf16(av[i], bv[j], acc[i][j], 0, 0, 0);
    __syncthreads();
  }

  // epilogue: bias + swiglu (odd-col term is the constant 8.0 -- source bug)
  const int mbase = mt * 128 + wm * 64;
  #pragma unroll
  for (int j = 0; j < 4; ++j) {
    const int ncol = n0 + wn * 64 + j * 16 + l16;
    const float bias = b1[(size_t)e * I2 + 2 * ncol];
    #pragma unroll
    for (int i = 0; i < 4; ++i) {
      #pragma unroll
      for (int rg = 0; rg < 4; ++rg) {
        const int gm = mbase + i * 16 + quad * 4 + rg;
        if (gm < rows) {
          const float h  = acc[i][j][rg] + bias;
          const float xg = fminf(h, 7.0f);
          const float s  = xg * (1.0f / (1.0f + __expf(-1.702f * xg))) * 8.0f;
          sBuf[((size_t)soff + gm) * IDIM + ncol] = (bf16)s;
        }
      }
    }
  }
}

// ------ Kernel 4: grouped GEMM2 + bias + weighted atomic scatter-add ---------
// y[m,h] = sum_i s[m,i] * w2[e][h][i] + b2[e][h]; out[tok] += w * y
template <bool PREP>
__global__ __launch_bounds__(256) void k_gemm2(
    const bf16* __restrict__ sBuf, const float* __restrict__ w2,
    const bf16* __restrict__ w2b, const float* __restrict__ b2,
    const int* __restrict__ cnt, const int* __restrict__ segOff,
    const int* __restrict__ rowTok, const float* __restrict__ rowW,
    float* __restrict__ out)
{
  const int e = blockIdx.z, mt = blockIdx.y, nt = blockIdx.x;
  const int rows = cnt[e];
  if (mt * 128 >= rows) return;
  const int soff = segOff[e];
  __shared__ __align__(16) bf16 Asm[128 * 32];
  __shared__ __align__(16) bf16 Bsm[128 * 32];
  const int tid = threadIdx.x;
  const int wid = tid >> 6, lane = tid & 63;
  const int quad = lane >> 4, l16 = lane & 15;
  const int wm = wid & 1, wn = wid >> 1;

  const int r0 = wid * 16 + (lane >> 2);
  const int r1 = 64 + r0;
  const int colE = (lane & 3) * 8;
  const int m0 = min(mt * 128 + r0, rows - 1);
  const int m1 = min(mt * 128 + r1, rows - 1);
  const char* gA0 = (const char*)(sBuf + ((size_t)soff + m0) * IDIM + colE);
  const char* gA1 = (const char*)(sBuf + ((size_t)soff + m1) * IDIM + colE);
  bf16* lA0 = Asm + wid * 512;
  bf16* lA1 = Asm + 2048 + wid * 512;

  const int n0 = nt * 128;
  const char* gB0 = (const char*)(w2b + (size_t)e * HD * IDIM + (size_t)(n0 + r0) * IDIM + colE);
  const char* gB1 = (const char*)(w2b + (size_t)e * HD * IDIM + (size_t)(n0 + r1) * IDIM + colE);
  bf16* lB0 = Bsm + wid * 512;
  bf16* lB1 = Bsm + 2048 + wid * 512;
  const int brow = tid >> 3;
  const int bkk  = (tid & 7) * 4;
  const float* gB = w2 + (size_t)e * HD * IDIM + (size_t)(n0 + brow) * IDIM + bkk;

  const f32x4 zero = {0.f, 0.f, 0.f, 0.f};
  f32x4 acc[4][4];
  #pragma unroll
  for (int i = 0; i < 4; ++i)
    #pragma unroll
    for (int j = 0; j < 4; ++j) acc[i][j] = zero;

  for (int kt = 0; kt < 32; ++kt) {
    async_copy16(gA0, lA0);
    async_copy16(gA1, lA1);
    gA0 += 64; gA1 += 64;
    if constexpr (PREP) {
      async_copy16(gB0, lB0);
      async_copy16(gB1, lB1);
      gB0 += 64; gB1 += 64;
    } else {
      #pragma unroll
      for (int q = 0; q < 4; ++q) {
        const float4 v = *(const float4*)(gB + (size_t)q * 32 * IDIM);
        bf16x4 c;
        c[0] = (bf16)v.x; c[1] = (bf16)v.y; c[2] = (bf16)v.z; c[3] = (bf16)v.w;
        *(bf16x4*)(Bsm + (q * 32 + brow) * 32 + bkk) = c;
      }
      gB += 32;
    }
    __syncthreads();
    bf16x8 av[4], bv[4];
    #pragma unroll
    for (int i = 0; i < 4; ++i)
      av[i] = *(const bf16x8*)(Asm + (wm * 64 + i * 16 + l16) * 32 + quad * 8);
    #pragma unroll
    for (int j = 0; j < 4; ++j)
      bv[j] = *(const bf16x8*)(Bsm + (wn * 64 + j * 16 + l16) * 32 + quad * 8);
    #pragma unroll
    for (int i = 0; i < 4; ++i)
      #pragma unroll
      for (int j = 0; j < 4; ++j)
        acc[i][j] = __builtin_amdgcn_mfma_f32_16x16x32_bf16(av[i], bv[j], acc[i][j], 0, 0, 0);
    __syncthreads();
  }

  const int mbase = mt * 128 + wm * 64;
  #pragma unroll
  for (int j = 0; j < 4; ++j) {
    const int ncol = n0 + wn * 64 + j * 16 + l16;
    const float bias = b2[(size_t)e * HD + ncol];
    #pragma unroll
    for (int i = 0; i < 4; ++i) {
      #pragma unroll
      for (int rg = 0; rg < 4; ++rg) {
        const int gm = mbase + i * 16 + quad * 4 + rg;
        if (gm < rows) {
          const int   tok = rowTok[soff + gm];
          const float wgt = rowW[soff + gm];
          atomicAdd(out + (size_t)tok * HD + ncol, wgt * (acc[i][j][rg] + bias));
        }
      }
    }
  }
}

// ---------------- launch -----------------------------------------------------
extern "C" void kernel_launch(void* const* d_in, const int* in_sizes, int n_in,
                              void* d_out, int out_size, void* d_ws, size_t ws_size,
                              hipStream_t stream) {
  const float* x      = (const float*)d_in[0];
  const float* scale  = (const float*)d_in[1];
  const float* gate_w = (const float*)d_in[2];
  const float* gate_b = (const float*)d_in[3];
  const float* w1     = (const float*)d_in[4];
  const float* b1     = (const float*)d_in[5];
  const float* w2     = (const float*)d_in[6];
  const float* b2     = (const float*)d_in[7];
  float* out = (float*)d_out;

  // base workspace: 21.1 MB, byte-identical to round 3 (proven safe)
  char* p = (char*)d_ws;
  bf16* tN   = (bf16*)p;  p += (size_t)TKN * HD * 2;        // 4 MB
  bf16* sBuf = (bf16*)p;  p += (size_t)NROW * IDIM * 2;     // 16 MB
  int*   eids   = (int*)p;   p += (size_t)NROW * 4;         // 32 KB
  float* wts    = (float*)p; p += (size_t)NROW * 4;         // 32 KB
  int*   rowTok = (int*)p;   p += (size_t)NROW * 4;         // 32 KB
  float* rowW   = (float*)p; p += (size_t)NROW * 4;         // 32 KB
  int*   cntg   = (int*)p;   p += 256;
  int*   segg   = (int*)p;   p += 256;
  const size_t base_need = (size_t)(p - (char*)d_ws);
  // tiered extras (guarded; round-2 fault traced to UNguarded base growth)
  const size_t WSZ = (size_t)NEXP * IDIM * HD * 2;          // 33.55 MB each
  bf16* w2b = (bf16*)p;
  bf16* w1b = (bf16*)(p + WSZ);
  const bool prep2 = ws_size >= base_need + WSZ;
  const bool prep1 = ws_size >= base_need + 2 * WSZ;

  k_norm_gate<<<TKN, 256, 0, stream>>>(x, scale, gate_w, gate_b, out, tN, eids, wts);
  k_route<<<1, 256, 0, stream>>>(eids, wts, cntg, segg, rowTok, rowW);
  if (prep1) k_cvt_w1<<<8192, 256, 0, stream>>>(w1, w1b);
  if (prep2) k_cvt_w2<<<8192, 256, 0, stream>>>(w2, w2b);

  if (prep1)
    k_gemm1<true><<<dim3(8, 16, NEXP), 256, 0, stream>>>(tN, w1, w1b, b1, cntg, segg, rowTok, sBuf);
  else
    k_gemm1<false><<<dim3(8, 16, NEXP), 256, 0, stream>>>(tN, w1, w1b, b1, cntg, segg, rowTok, sBuf);

  if (prep2)
    k_gemm2<true><<<dim3(8, 16, NEXP), 256, 0, stream>>>(sBuf, w2, w2b, b2, cntg, segg, rowTok, rowW, out);
  else
    k_gemm2<false><<<dim3(8, 16, NEXP), 256, 0, stream>>>(sBuf, w2, w2b, b2, cntg, segg, rowTok, rowW, out);
}

// Round 5
// 380.125 us; speedup vs baseline: 1.2334x; 1.0203x over previous
//
#include <hip/hip_runtime.h>
#include <hip/hip_bf16.h>

typedef __bf16 bf16;
typedef __bf16 bf16x4 __attribute__((ext_vector_type(4)));
typedef __bf16 bf16x8 __attribute__((ext_vector_type(8)));
typedef float f32x4 __attribute__((ext_vector_type(4)));

constexpr int TKN  = 2048;   // tokens
constexpr int HD   = 1024;   // hidden
constexpr int NEXP = 16;     // experts
constexpr int KSEL = 4;      // top-k
constexpr int IDIM = 1024;   // I
constexpr int I2   = 2048;   // 2*I
constexpr int NROW = TKN * KSEL;  // 8192 token-expert rows

// async global->LDS, 16B per lane; global addr per-lane, LDS dest = wave-uniform
// base + lane*16.
__device__ __forceinline__ void async_copy16(const void* g, void* l) {
  __builtin_amdgcn_global_load_lds((__attribute__((address_space(1))) void*)g,
                                   (__attribute__((address_space(3))) void*)l,
                                   16, 0, 0);
}

// ------ Kernel 1: RMSNorm + fp32 gate + top-4 (NO global atomics) + out=x ----
__global__ __launch_bounds__(256) void k_norm_gate(
    const float* __restrict__ x, const float* __restrict__ scale,
    const float* __restrict__ gate_w, const float* __restrict__ gate_b,
    float* __restrict__ out, bf16* __restrict__ tN,
    int* __restrict__ eids, float* __restrict__ wts)
{
  __shared__ float tLds[HD];
  __shared__ float red[4];
  __shared__ float gsh[NEXP];
  const int tid = threadIdx.x;
  const int tok = blockIdx.x;
  const int wid = tid >> 6, lane = tid & 63;

  const float4 x4 = *(const float4*)(x + (size_t)tok * HD + tid * 4);
  float ss = x4.x * x4.x + x4.y * x4.y + x4.z * x4.z + x4.w * x4.w;
  #pragma unroll
  for (int off = 32; off > 0; off >>= 1) ss += __shfl_down(ss, off);
  if (lane == 0) red[wid] = ss;
  __syncthreads();
  ss = red[0] + red[1] + red[2] + red[3];
  const float r = rsqrtf(ss * (1.0f / HD) + 1e-5f);

  const float4 s4 = *(const float4*)(scale + tid * 4);
  float4 t4;
  t4.x = x4.x * r * s4.x; t4.y = x4.y * r * s4.y;
  t4.z = x4.z * r * s4.z; t4.w = x4.w * r * s4.w;
  *(float4*)(out + (size_t)tok * HD + tid * 4) = x4;   // residual init
  tLds[tid * 4 + 0] = t4.x; tLds[tid * 4 + 1] = t4.y;
  tLds[tid * 4 + 2] = t4.z; tLds[tid * 4 + 3] = t4.w;
  bf16x4 tb;
  tb[0] = (bf16)t4.x; tb[1] = (bf16)t4.y; tb[2] = (bf16)t4.z; tb[3] = (bf16)t4.w;
  *(bf16x4*)(tN + (size_t)tok * HD + tid * 4) = tb;
  __syncthreads();

  {
    const int e = tid >> 4, l16 = tid & 15;
    float p = 0.f;
    const float* gw = gate_w + (size_t)e * HD;
    for (int j = l16; j < HD; j += 16) p += tLds[j] * gw[j];
    p += __shfl_xor(p, 8); p += __shfl_xor(p, 4);
    p += __shfl_xor(p, 2); p += __shfl_xor(p, 1);
    if (l16 == 0) gsh[e] = p + gate_b[e];
  }
  __syncthreads();

  if (tid == 0) {
    float g[NEXP];
    #pragma unroll
    for (int i = 0; i < NEXP; ++i) g[i] = gsh[i];
    int   bi[KSEL]; float bv[KSEL];
    #pragma unroll
    for (int k = 0; k < KSEL; ++k) {
      float best = -1e30f; int b = 0;
      for (int i = 0; i < NEXP; ++i) if (g[i] > best) { best = g[i]; b = i; }
      bv[k] = best; bi[k] = b; g[b] = -1e30f;
    }
    const float m = bv[0];
    float wv[KSEL], sum = 0.f;
    #pragma unroll
    for (int k = 0; k < KSEL; ++k) { wv[k] = __expf(bv[k] - m); sum += wv[k]; }
    const float inv = 1.0f / sum;
    #pragma unroll
    for (int k = 0; k < KSEL; ++k) {
      eids[tok * KSEL + k] = bi[k];
      wts[tok * KSEL + k]  = wv[k] * inv;
    }
  }
}

// ------ Kernel 2: bucket build (single block, LDS atomics only) --------------
__global__ __launch_bounds__(256) void k_route(
    const int* __restrict__ eids, const float* __restrict__ wts,
    int* __restrict__ cntg, int* __restrict__ segg,
    int* __restrict__ rowTok, float* __restrict__ rowW, int* __restrict__ rowOf)
{
  __shared__ int hcnt[NEXP], hoff[NEXP], hrun[NEXP];
  const int tid = threadIdx.x;
  if (tid < NEXP) { hcnt[tid] = 0; hrun[tid] = 0; }
  __syncthreads();
  for (int i = tid; i < NROW; i += 256) atomicAdd(&hcnt[eids[i]], 1);
  __syncthreads();
  if (tid == 0) {
    int s = 0;
    for (int e = 0; e < NEXP; ++e) { hoff[e] = s; segg[e] = s; cntg[e] = hcnt[e]; s += hcnt[e]; }
  }
  __syncthreads();
  for (int i = tid; i < NROW; i += 256) {
    const int e = eids[i];
    const int slot = atomicAdd(&hrun[e], 1);
    const int row = hoff[e] + slot;
    rowTok[row] = i >> 2;
    rowW[row]   = wts[i];
    rowOf[i]    = row;             // (tok,k) -> compact row
  }
}

// ------ merged weight conversion fp32 -> bf16 (w1 even rows only + w2) -------
__global__ __launch_bounds__(256) void k_cvt_all(const float* __restrict__ w1,
                                                 const float* __restrict__ w2,
                                                 bf16* __restrict__ w1b,
                                                 bf16* __restrict__ w2b) {
  const size_t bid = blockIdx.x;
  if (bid < 8192) {
    const size_t f = bid * 256 + threadIdx.x;
    const size_t row = f >> 7;
    const int    off = (int)(f & 127) * 8;
    const size_t e = row >> 10, n = row & 1023;
    const float* s = w1 + (e * 2048 + 2 * n) * 1024 + off;
    const float4 a = *(const float4*)(s);
    const float4 b = *(const float4*)(s + 4);
    bf16x8 o;
    o[0] = (bf16)a.x; o[1] = (bf16)a.y; o[2] = (bf16)a.z; o[3] = (bf16)a.w;
    o[4] = (bf16)b.x; o[5] = (bf16)b.y; o[6] = (bf16)b.z; o[7] = (bf16)b.w;
    *(bf16x8*)(w1b + row * 1024 + off) = o;
  } else {
    const size_t f = (bid - 8192) * 256 + threadIdx.x;
    const size_t base = f * 8;
    const float4 a = *(const float4*)(w2 + base);
    const float4 b = *(const float4*)(w2 + base + 4);
    bf16x8 o;
    o[0] = (bf16)a.x; o[1] = (bf16)a.y; o[2] = (bf16)a.z; o[3] = (bf16)a.w;
    o[4] = (bf16)b.x; o[5] = (bf16)b.y; o[6] = (bf16)b.z; o[7] = (bf16)b.w;
    *(bf16x8*)(w2b + base) = o;
  }
}

// ====== v2 GEMMs: tile 64(M)x128(N), BK=64 as two 32-k sub-tiles =============
// LDS stride stays 32 bf16 (64 B) per row -- the proven m97 layout.

// ------ Kernel 3 v2: grouped GEMM1 + SwiGLU ----------------------------------
__global__ __launch_bounds__(256) void k_gemm1v2(
    const bf16* __restrict__ tN, const bf16* __restrict__ w1b,
    const float* __restrict__ b1, const int* __restrict__ cnt,
    const int* __restrict__ segOff, const int* __restrict__ rowTok,
    bf16* __restrict__ sBuf)
{
  const int e = blockIdx.z, mt = blockIdx.y, nt = blockIdx.x;
  const int rows = cnt[e];
  if (mt * 64 >= rows) return;
  const int soff = segOff[e];
  __shared__ __align__(16) bf16 Asm[2 * 64 * 32];    // 8 KB (sub0, sub1)
  __shared__ __align__(16) bf16 Bsm[2 * 128 * 32];   // 16 KB
  const int tid = threadIdx.x;
  const int wid = tid >> 6, lane = tid & 63;
  const int quad = lane >> 4, l16 = lane & 15;
  const int wm = wid & 1, wn = wid >> 1;

  const int r0 = wid * 16 + (lane >> 2);     // [0,64)
  const int colE = (lane & 3) * 8;           // bf16 col within 32-k sub-tile
  const int mA = min(mt * 64 + r0, rows - 1);
  const char* gA  = (const char*)(tN + (size_t)rowTok[soff + mA] * HD + colE);
  const int n0 = nt * 128;
  const char* gB0 = (const char*)(w1b + ((size_t)e * IDIM + n0 + r0) * HD + colE);
  const char* gB1 = (const char*)(w1b + ((size_t)e * IDIM + n0 + 64 + r0) * HD + colE);
  bf16* lA  = Asm + wid * 512;               // rows wid*16..+15, sub0
  bf16* lB0 = Bsm + wid * 512;               // rows 0..63, sub0
  bf16* lB1 = Bsm + 2048 + wid * 512;        // rows 64..127, sub0

  const f32x4 zero = {0.f, 0.f, 0.f, 0.f};
  f32x4 acc[2][4];
  #pragma unroll
  for (int i = 0; i < 2; ++i)
    #pragma unroll
    for (int j = 0; j < 4; ++j) acc[i][j] = zero;

  for (int kt = 0; kt < 16; ++kt) {
    async_copy16(gA, lA);                    // sub0
    async_copy16(gB0, lB0);
    async_copy16(gB1, lB1);
    async_copy16(gA + 64, lA + 2048);        // sub1 (+64 B glob, +4 KB lds)
    async_copy16(gB0 + 64, lB0 + 4096);
    async_copy16(gB1 + 64, lB1 + 4096);
    gA += 128; gB0 += 128; gB1 += 128;
    __syncthreads();
    bf16x8 av[2];
    #pragma unroll
    for (int s = 0; s < 2; ++s) {
      av[0] = *(const bf16x8*)(Asm + s * 2048 + (wm * 32 + 0 * 16 + l16) * 32 + quad * 8);
      av[1] = *(const bf16x8*)(Asm + s * 2048 + (wm * 32 + 1 * 16 + l16) * 32 + quad * 8);
      #pragma unroll
      for (int j = 0; j < 4; ++j) {
        const bf16x8 bv = *(const bf16x8*)(Bsm + s * 4096 + (wn * 64 + j * 16 + l16) * 32 + quad * 8);
        acc[0][j] = __builtin_amdgcn_mfma_f32_16x16x32_bf16(av[0], bv, acc[0][j], 0, 0, 0);
        acc[1][j] = __builtin_amdgcn_mfma_f32_16x16x32_bf16(av[1], bv, acc[1][j], 0, 0, 0);
      }
    }
    __syncthreads();
  }

  const int mbase = mt * 64 + wm * 32;
  #pragma unroll
  for (int j = 0; j < 4; ++j) {
    const int ncol = n0 + wn * 64 + j * 16 + l16;
    const float bias = b1[(size_t)e * I2 + 2 * ncol];
    #pragma unroll
    for (int i = 0; i < 2; ++i) {
      #pragma unroll
      for (int rg = 0; rg < 4; ++rg) {
        const int gm = mbase + i * 16 + quad * 4 + rg;
        if (gm < rows) {
          const float h  = acc[i][j][rg] + bias;
          const float xg = fminf(h, 7.0f);
          const float s  = xg * (1.0f / (1.0f + __expf(-1.702f * xg))) * 8.0f;
          sBuf[((size_t)soff + gm) * IDIM + ncol] = (bf16)s;
        }
      }
    }
  }
}

// ------ Kernel 4 v2: grouped GEMM2; epilogue = yBuf stores or atomic ---------
template <bool USEY>
__global__ __launch_bounds__(256) void k_gemm2v2(
    const bf16* __restrict__ sBuf, const bf16* __restrict__ w2b,
    const float* __restrict__ b2, const int* __restrict__ cnt,
    const int* __restrict__ segOff, const int* __restrict__ rowTok,
    const float* __restrict__ rowW, bf16* __restrict__ yBuf,
    float* __restrict__ out)
{
  const int e = blockIdx.z, mt = blockIdx.y, nt = blockIdx.x;
  const int rows = cnt[e];
  if (mt * 64 >= rows) return;
  const int soff = segOff[e];
  __shared__ __align__(16) bf16 Asm[2 * 64 * 32];
  __shared__ __align__(16) bf16 Bsm[2 * 128 * 32];
  const int tid = threadIdx.x;
  const int wid = tid >> 6, lane = tid & 63;
  const int quad = lane >> 4, l16 = lane & 15;
  const int wm = wid & 1, wn = wid >> 1;

  const int r0 = wid * 16 + (lane >> 2);
  const int colE = (lane & 3) * 8;
  const int mA = min(mt * 64 + r0, rows - 1);
  const char* gA  = (const char*)(sBuf + ((size_t)soff + mA) * IDIM + colE);
  const int n0 = nt * 128;
  const char* gB0 = (const char*)(w2b + ((size_t)e * HD + n0 + r0) * IDIM + colE);
  const char* gB1 = (const char*)(w2b + ((size_t)e * HD + n0 + 64 + r0) * IDIM + colE);
  bf16* lA  = Asm + wid * 512;
  bf16* lB0 = Bsm + wid * 512;
  bf16* lB1 = Bsm + 2048 + wid * 512;

  const f32x4 zero = {0.f, 0.f, 0.f, 0.f};
  f32x4 acc[2][4];
  #pragma unroll
  for (int i = 0; i < 2; ++i)
    #pragma unroll
    for (int j = 0; j < 4; ++j) acc[i][j] = zero;

  for (int kt = 0; kt < 16; ++kt) {
    async_copy16(gA, lA);
    async_copy16(gB0, lB0);
    async_copy16(gB1, lB1);
    async_copy16(gA + 64, lA + 2048);
    async_copy16(gB0 + 64, lB0 + 4096);
    async_copy16(gB1 + 64, lB1 + 4096);
    gA += 128; gB0 += 128; gB1 += 128;
    __syncthreads();
    bf16x8 av[2];
    #pragma unroll
    for (int s = 0; s < 2; ++s) {
      av[0] = *(const bf16x8*)(Asm + s * 2048 + (wm * 32 + 0 * 16 + l16) * 32 + quad * 8);
      av[1] = *(const bf16x8*)(Asm + s * 2048 + (wm * 32 + 1 * 16 + l16) * 32 + quad * 8);
      #pragma unroll
      for (int j = 0; j < 4; ++j) {
        const bf16x8 bv = *(const bf16x8*)(Bsm + s * 4096 + (wn * 64 + j * 16 + l16) * 32 + quad * 8);
        acc[0][j] = __builtin_amdgcn_mfma_f32_16x16x32_bf16(av[0], bv, acc[0][j], 0, 0, 0);
        acc[1][j] = __builtin_amdgcn_mfma_f32_16x16x32_bf16(av[1], bv, acc[1][j], 0, 0, 0);
      }
    }
    __syncthreads();
  }

  const int mbase = mt * 64 + wm * 32;
  #pragma unroll
  for (int j = 0; j < 4; ++j) {
    const int ncol = n0 + wn * 64 + j * 16 + l16;
    const float bias = b2[(size_t)e * HD + ncol];
    #pragma unroll
    for (int i = 0; i < 2; ++i) {
      #pragma unroll
      for (int rg = 0; rg < 4; ++rg) {
        const int gm = mbase + i * 16 + quad * 4 + rg;
        if (gm < rows) {
          if constexpr (USEY) {
            yBuf[((size_t)soff + gm) * HD + ncol] = (bf16)(acc[i][j][rg] + bias);
          } else {
            atomicAdd(out + (size_t)rowTok[soff + gm] * HD + ncol,
                      rowW[soff + gm] * (acc[i][j][rg] + bias));
          }
        }
      }
    }
  }
}

// ------ Kernel 5: finalize  out = x + sum_k w_k * y_k ------------------------
__global__ __launch_bounds__(256) void k_finalize(
    const float* __restrict__ x, const bf16* __restrict__ yBuf,
    const int* __restrict__ rowOf, const float* __restrict__ wts,
    float* __restrict__ out)
{
  const int tok = blockIdx.x;
  const int tid = threadIdx.x;
  const int r0 = rowOf[tok * 4 + 0], r1 = rowOf[tok * 4 + 1];
  const int r2 = rowOf[tok * 4 + 2], r3 = rowOf[tok * 4 + 3];
  const float w0 = wts[tok * 4 + 0], w1 = wts[tok * 4 + 1];
  const float w2 = wts[tok * 4 + 2], w3 = wts[tok * 4 + 3];
  const int col = tid * 4;
  float4 o = *(const float4*)(x + (size_t)tok * HD + col);
  const bf16x4 y0 = *(const bf16x4*)(yBuf + (size_t)r0 * HD + col);
  const bf16x4 y1 = *(const bf16x4*)(yBuf + (size_t)r1 * HD + col);
  const bf16x4 y2 = *(const bf16x4*)(yBuf + (size_t)r2 * HD + col);
  const bf16x4 y3 = *(const bf16x4*)(yBuf + (size_t)r3 * HD + col);
  o.x += w0 * (float)y0[0] + w1 * (float)y1[0] + w2 * (float)y2[0] + w3 * (float)y3[0];
  o.y += w0 * (float)y0[1] + w1 * (float)y1[1] + w2 * (float)y2[1] + w3 * (float)y3[1];
  o.z += w0 * (float)y0[2] + w1 * (float)y1[2] + w2 * (float)y2[2] + w3 * (float)y3[2];
  o.w += w0 * (float)y0[3] + w1 * (float)y1[3] + w2 * (float)y2[3] + w3 * (float)y3[3];
  *(float4*)(out + (size_t)tok * HD + col) = o;
}

// ====== round-4 fallback GEMMs (128x128, BK=32, fp32 B in-loop convert) ======
__global__ __launch_bounds__(256) void k_gemm1_fb(
    const bf16* __restrict__ tN, const float* __restrict__ w1,
    const float* __restrict__ b1, const int* __restrict__ cnt,
    const int* __restrict__ segOff, const int* __restrict__ rowTok,
    bf16* __restrict__ sBuf)
{
  const int e = blockIdx.z, mt = blockIdx.y, nt = blockIdx.x;
  const int rows = cnt[e];
  if (mt * 128 >= rows) return;
  const int soff = segOff[e];
  __shared__ __align__(16) bf16 Asm[128 * 32];
  __shared__ __align__(16) bf16 Bsm[128 * 32];
  const int tid = threadIdx.x;
  const int wid = tid >> 6, lane = tid & 63;
  const int quad = lane >> 4, l16 = lane & 15;
  const int wm = wid & 1, wn = wid >> 1;
  const int r0 = wid * 16 + (lane >> 2);
  const int r1 = 64 + r0;
  const int colE = (lane & 3) * 8;
  const int m0 = min(mt * 128 + r0, rows - 1);
  const int m1 = min(mt * 128 + r1, rows - 1);
  const char* gA0 = (const char*)(tN + (size_t)rowTok[soff + m0] * HD + colE);
  const char* gA1 = (const char*)(tN + (size_t)rowTok[soff + m1] * HD + colE);
  bf16* lA0 = Asm + wid * 512;
  bf16* lA1 = Asm + 2048 + wid * 512;
  const int brow = tid >> 3;
  const int bkk  = (tid & 7) * 4;
  const int n0 = nt * 128;
  const float* gB = w1 + (size_t)e * I2 * HD + (size_t)(2 * (n0 + brow)) * HD + bkk;

  const f32x4 zero = {0.f, 0.f, 0.f, 0.f};
  f32x4 acc[4][4];
  #pragma unroll
  for (int i = 0; i < 4; ++i)
    #pragma unroll
    for (int j = 0; j < 4; ++j) acc[i][j] = zero;

  for (int kt = 0; kt < 32; ++kt) {
    async_copy16(gA0, lA0);
    async_copy16(gA1, lA1);
    gA0 += 64; gA1 += 64;
    #pragma unroll
    for (int q = 0; q < 4; ++q) {
      const float4 v = *(const float4*)(gB + (size_t)q * 64 * HD);
      bf16x4 c;
      c[0] = (bf16)v.x; c[1] = (bf16)v.y; c[2] = (bf16)v.z; c[3] = (bf16)v.w;
      *(bf16x4*)(Bsm + (q * 32 + brow) * 32 + bkk) = c;
    }
    gB += 32;
    __syncthreads();
    bf16x8 av[4], bv[4];
    #pragma unroll
    for (int i = 0; i < 4; ++i)
      av[i] = *(const bf16x8*)(Asm + (wm * 64 + i * 16 + l16) * 32 + quad * 8);
    #pragma unroll
    for (int j = 0; j < 4; ++j)
      bv[j] = *(const bf16x8*)(Bsm + (wn * 64 + j * 16 + l16) * 32 + quad * 8);
    #pragma unroll
    for (int i = 0; i < 4; ++i)
      #pragma unroll
      for (int j = 0; j < 4; ++j)
        acc[i][j] = __builtin_amdgcn_mfma_f32_16x16x32_bf16(av[i], bv[j], acc[i][j], 0, 0, 0);
    __syncthreads();
  }
  const int mbase = mt * 128 + wm * 64;
  #pragma unroll
  for (int j = 0; j < 4; ++j) {
    const int ncol = n0 + wn * 64 + j * 16 + l16;
    const float bias = b1[(size_t)e * I2 + 2 * ncol];
    #pragma unroll
    for (int i = 0; i < 4; ++i) {
      #pragma unroll
      for (int rg = 0; rg < 4; ++rg) {
        const int gm = mbase + i * 16 + quad * 4 + rg;
        if (gm < rows) {
          const float h  = acc[i][j][rg] + bias;
          const float xg = fminf(h, 7.0f);
          const float s  = xg * (1.0f / (1.0f + __expf(-1.702f * xg))) * 8.0f;
          sBuf[((size_t)soff + gm) * IDIM + ncol] = (bf16)s;
        }
      }
    }
  }
}

__global__ __launch_bounds__(256) void k_gemm2_fb(
    const bf16* __restrict__ sBuf, const float* __restrict__ w2,
    const float* __restrict__ b2, const int* __restrict__ cnt,
    const int* __restrict__ segOff, const int* __restrict__ rowTok,
    const float* __restrict__ rowW, float* __restrict__ out)
{
  const int e = blockIdx.z, mt = blockIdx.y, nt = blockIdx.x;
  const int rows = cnt[e];
  if (mt * 128 >= rows) return;
  const int soff = segOff[e];
  __shared__ __align__(16) bf16 Asm[128 * 32];
  __shared__ __align__(16) bf16 Bsm[128 * 32];
  const int tid = threadIdx.x;
  const int wid = tid >> 6, lane = tid & 63;
  const int quad = lane >> 4, l16 = lane & 15;
  const int wm = wid & 1, wn = wid >> 1;
  const int r0 = wid * 16 + (lane >> 2);
  const int r1 = 64 + r0;
  const int colE = (lane & 3) * 8;
  const int m0 = min(mt * 128 + r0, rows - 1);
  const int m1 = min(mt * 128 + r1, rows - 1);
  const char* gA0 = (const char*)(sBuf + ((size_t)soff + m0) * IDIM + colE);
  const char* gA1 = (const char*)(sBuf + ((size_t)soff + m1) * IDIM + colE);
  bf16* lA0 = Asm + wid * 512;
  bf16* lA1 = Asm + 2048 + wid * 512;
  const int brow = tid >> 3;
  const int bkk  = (tid & 7) * 4;
  const int n0 = nt * 128;
  const float* gB = w2 + (size_t)e * HD * IDIM + (size_t)(n0 + brow) * IDIM + bkk;

  const f32x4 zero = {0.f, 0.f, 0.f, 0.f};
  f32x4 acc[4][4];
  #pragma unroll
  for (int i = 0; i < 4; ++i)
    #pragma unroll
    for (int j = 0; j < 4; ++j) acc[i][j] = zero;

  for (int kt = 0; kt < 32; ++kt) {
    async_copy16(gA0, lA0);
    async_copy16(gA1, lA1);
    gA0 += 64; gA1 += 64;
    #pragma unroll
    for (int q = 0; q < 4; ++q) {
      const float4 v = *(const float4*)(gB + (size_t)q * 32 * IDIM);
      bf16x4 c;
      c[0] = (bf16)v.x; c[1] = (bf16)v.y; c[2] = (bf16)v.z; c[3] = (bf16)v.w;
      *(bf16x4*)(Bsm + (q * 32 + brow) * 32 + bkk) = c;
    }
    gB += 32;
    __syncthreads();
    bf16x8 av[4], bv[4];
    #pragma unroll
    for (int i = 0; i < 4; ++i)
      av[i] = *(const bf16x8*)(Asm + (wm * 64 + i * 16 + l16) * 32 + quad * 8);
    #pragma unroll
    for (int j = 0; j < 4; ++j)
      bv[j] = *(const bf16x8*)(Bsm + (wn * 64 + j * 16 + l16) * 32 + quad * 8);
    #pragma unroll
    for (int i = 0; i < 4; ++i)
      #pragma unroll
      for (int j = 0; j < 4; ++j)
        acc[i][j] = __builtin_amdgcn_mfma_f32_16x16x32_bf16(av[i], bv[j], acc[i][j], 0, 0, 0);
    __syncthreads();
  }
  const int mbase = mt * 128 + wm * 64;
  #pragma unroll
  for (int j = 0; j < 4; ++j) {
    const int ncol = n0 + wn * 64 + j * 16 + l16;
    const float bias = b2[(size_t)e * HD + ncol];
    #pragma unroll
    for (int i = 0; i < 4; ++i) {
      #pragma unroll
      for (int rg = 0; rg < 4; ++rg) {
        const int gm = mbase + i * 16 + quad * 4 + rg;
        if (gm < rows) {
          atomicAdd(out + (size_t)rowTok[soff + gm] * HD + ncol,
                    rowW[soff + gm] * (acc[i][j][rg] + bias));
        }
      }
    }
  }
}

// ---------------- launch -----------------------------------------------------
extern "C" void kernel_launch(void* const* d_in, const int* in_sizes, int n_in,
                              void* d_out, int out_size, void* d_ws, size_t ws_size,
                              hipStream_t stream) {
  const float* x      = (const float*)d_in[0];
  const float* scale  = (const float*)d_in[1];
  const float* gate_w = (const float*)d_in[2];
  const float* gate_b = (const float*)d_in[3];
  const float* w1     = (const float*)d_in[4];
  const float* b1     = (const float*)d_in[5];
  const float* w2     = (const float*)d_in[6];
  const float* b2     = (const float*)d_in[7];
  float* out = (float*)d_out;

  // base workspace (~21.2 MB)
  char* p = (char*)d_ws;
  bf16* tN   = (bf16*)p;  p += (size_t)TKN * HD * 2;        // 4 MB
  bf16* sBuf = (bf16*)p;  p += (size_t)NROW * IDIM * 2;     // 16 MB
  int*   eids   = (int*)p;   p += (size_t)NROW * 4;
  float* wts    = (float*)p; p += (size_t)NROW * 4;
  int*   rowTok = (int*)p;   p += (size_t)NROW * 4;
  float* rowW   = (float*)p; p += (size_t)NROW * 4;
  int*   rowOf  = (int*)p;   p += (size_t)NROW * 4;
  int*   cntg   = (int*)p;   p += 256;
  int*   segg   = (int*)p;   p += 256;
  const size_t base_need = (size_t)(p - (char*)d_ws);
  const size_t WSZ = (size_t)NEXP * IDIM * HD * 2;          // 33.55 MB each
  bf16* w2b  = (bf16*)p;
  bf16* w1b  = (bf16*)(p + WSZ);
  bf16* yBuf = (bf16*)(p + 2 * WSZ);                        // 16 MB
  const bool prep2 = ws_size >= base_need + WSZ;
  const bool prep1 = ws_size >= base_need + 2 * WSZ;
  const bool useY  = prep1 && prep2 &&
                     (ws_size >= base_need + 2 * WSZ + (size_t)NROW * HD * 2);

  k_norm_gate<<<TKN, 256, 0, stream>>>(x, scale, gate_w, gate_b, out, tN, eids, wts);
  k_route<<<1, 256, 0, stream>>>(eids, wts, cntg, segg, rowTok, rowW, rowOf);

  if (prep1 && prep2) {
    k_cvt_all<<<16384, 256, 0, stream>>>(w1, w2, w1b, w2b);
  }

  if (prep1 && prep2) {
    k_gemm1v2<<<dim3(8, 32, NEXP), 256, 0, stream>>>(tN, w1b, b1, cntg, segg, rowTok, sBuf);
    if (useY) {
      k_gemm2v2<true><<<dim3(8, 32, NEXP), 256, 0, stream>>>(sBuf, w2b, b2, cntg, segg,
                                                             rowTok, rowW, yBuf, out);
      k_finalize<<<TKN, 256, 0, stream>>>(x, yBuf, rowOf, wts, out);
    } else {
      k_gemm2v2<false><<<dim3(8, 32, NEXP), 256, 0, stream>>>(sBuf, w2b, b2, cntg, segg,
                                                              rowTok, rowW, yBuf, out);
    }
  } else {
    k_gemm1_fb<<<dim3(8, 16, NEXP), 256, 0, stream>>>(tN, w1, b1, cntg, segg, rowTok, sBuf);
    k_gemm2_fb<<<dim3(8, 16, NEXP), 256, 0, stream>>>(sBuf, w2, b2, cntg, segg, rowTok, rowW, out);
  }
}

// Round 6
// 379.193 us; speedup vs baseline: 1.2364x; 1.0025x over previous
//
#include <hip/hip_runtime.h>
#include <hip/hip_bf16.h>

typedef __bf16 bf16;
typedef __bf16 bf16x4 __attribute__((ext_vector_type(4)));
typedef __bf16 bf16x8 __attribute__((ext_vector_type(8)));
typedef float f32x4 __attribute__((ext_vector_type(4)));

constexpr int TKN  = 2048;   // tokens
constexpr int HD   = 1024;   // hidden
constexpr int NEXP = 16;     // experts
constexpr int KSEL = 4;      // top-k
constexpr int IDIM = 1024;   // I
constexpr int I2   = 2048;   // 2*I
constexpr int NROW = TKN * KSEL;  // 8192 token-expert rows

// async global->LDS, 16B per lane; global addr per-lane, LDS dest = wave-uniform
// base + lane*16.
__device__ __forceinline__ void async_copy16(const void* g, void* l) {
  __builtin_amdgcn_global_load_lds((__attribute__((address_space(1))) void*)g,
                                   (__attribute__((address_space(3))) void*)l,
                                   16, 0, 0);
}

// ------ Kernel 1: RMSNorm + fp32 gate + top-4 (NO global atomics) + out=x ----
__global__ __launch_bounds__(256) void k_norm_gate(
    const float* __restrict__ x, const float* __restrict__ scale,
    const float* __restrict__ gate_w, const float* __restrict__ gate_b,
    float* __restrict__ out, bf16* __restrict__ tN,
    int* __restrict__ eids, float* __restrict__ wts)
{
  __shared__ float tLds[HD];
  __shared__ float red[4];
  __shared__ float gsh[NEXP];
  const int tid = threadIdx.x;
  const int tok = blockIdx.x;
  const int wid = tid >> 6, lane = tid & 63;

  const float4 x4 = *(const float4*)(x + (size_t)tok * HD + tid * 4);
  float ss = x4.x * x4.x + x4.y * x4.y + x4.z * x4.z + x4.w * x4.w;
  #pragma unroll
  for (int off = 32; off > 0; off >>= 1) ss += __shfl_down(ss, off);
  if (lane == 0) red[wid] = ss;
  __syncthreads();
  ss = red[0] + red[1] + red[2] + red[3];
  const float r = rsqrtf(ss * (1.0f / HD) + 1e-5f);

  const float4 s4 = *(const float4*)(scale + tid * 4);
  float4 t4;
  t4.x = x4.x * r * s4.x; t4.y = x4.y * r * s4.y;
  t4.z = x4.z * r * s4.z; t4.w = x4.w * r * s4.w;
  *(float4*)(out + (size_t)tok * HD + tid * 4) = x4;   // residual init
  tLds[tid * 4 + 0] = t4.x; tLds[tid * 4 + 1] = t4.y;
  tLds[tid * 4 + 2] = t4.z; tLds[tid * 4 + 3] = t4.w;
  bf16x4 tb;
  tb[0] = (bf16)t4.x; tb[1] = (bf16)t4.y; tb[2] = (bf16)t4.z; tb[3] = (bf16)t4.w;
  *(bf16x4*)(tN + (size_t)tok * HD + tid * 4) = tb;
  __syncthreads();

  {
    const int e = tid >> 4, l16 = tid & 15;
    float p = 0.f;
    const float* gw = gate_w + (size_t)e * HD;
    for (int j = l16; j < HD; j += 16) p += tLds[j] * gw[j];
    p += __shfl_xor(p, 8); p += __shfl_xor(p, 4);
    p += __shfl_xor(p, 2); p += __shfl_xor(p, 1);
    if (l16 == 0) gsh[e] = p + gate_b[e];
  }
  __syncthreads();

  if (tid == 0) {
    float g[NEXP];
    #pragma unroll
    for (int i = 0; i < NEXP; ++i) g[i] = gsh[i];
    int   bi[KSEL]; float bv[KSEL];
    #pragma unroll
    for (int k = 0; k < KSEL; ++k) {
      float best = -1e30f; int b = 0;
      for (int i = 0; i < NEXP; ++i) if (g[i] > best) { best = g[i]; b = i; }
      bv[k] = best; bi[k] = b; g[b] = -1e30f;
    }
    const float m = bv[0];
    float wv[KSEL], sum = 0.f;
    #pragma unroll
    for (int k = 0; k < KSEL; ++k) { wv[k] = __expf(bv[k] - m); sum += wv[k]; }
    const float inv = 1.0f / sum;
    #pragma unroll
    for (int k = 0; k < KSEL; ++k) {
      eids[tok * KSEL + k] = bi[k];
      wts[tok * KSEL + k]  = wv[k] * inv;
    }
  }
}

// ------ Kernel 2: bucket build (single block, LDS atomics only) --------------
__global__ __launch_bounds__(256) void k_route(
    const int* __restrict__ eids, const float* __restrict__ wts,
    int* __restrict__ cntg, int* __restrict__ segg,
    int* __restrict__ rowTok, float* __restrict__ rowW, int* __restrict__ rowOf)
{
  __shared__ int hcnt[NEXP], hoff[NEXP], hrun[NEXP];
  const int tid = threadIdx.x;
  if (tid < NEXP) { hcnt[tid] = 0; hrun[tid] = 0; }
  __syncthreads();
  for (int i = tid; i < NROW; i += 256) atomicAdd(&hcnt[eids[i]], 1);
  __syncthreads();
  if (tid == 0) {
    int s = 0;
    for (int e = 0; e < NEXP; ++e) { hoff[e] = s; segg[e] = s; cntg[e] = hcnt[e]; s += hcnt[e]; }
  }
  __syncthreads();
  for (int i = tid; i < NROW; i += 256) {
    const int e = eids[i];
    const int slot = atomicAdd(&hrun[e], 1);
    const int row = hoff[e] + slot;
    rowTok[row] = i >> 2;
    rowW[row]   = wts[i];
    rowOf[i]    = row;             // (tok,k) -> compact row
  }
}

// ------ merged weight conversion fp32 -> bf16 (w1 even rows only + w2) -------
__global__ __launch_bounds__(256) void k_cvt_all(const float* __restrict__ w1,
                                                 const float* __restrict__ w2,
                                                 bf16* __restrict__ w1b,
                                                 bf16* __restrict__ w2b) {
  const size_t bid = blockIdx.x;
  if (bid < 8192) {
    const size_t f = bid * 256 + threadIdx.x;
    const size_t row = f >> 7;
    const int    off = (int)(f & 127) * 8;
    const size_t e = row >> 10, n = row & 1023;
    const float* s = w1 + (e * 2048 + 2 * n) * 1024 + off;
    const float4 a = *(const float4*)(s);
    const float4 b = *(const float4*)(s + 4);
    bf16x8 o;
    o[0] = (bf16)a.x; o[1] = (bf16)a.y; o[2] = (bf16)a.z; o[3] = (bf16)a.w;
    o[4] = (bf16)b.x; o[5] = (bf16)b.y; o[6] = (bf16)b.z; o[7] = (bf16)b.w;
    *(bf16x8*)(w1b + row * 1024 + off) = o;
  } else {
    const size_t f = (bid - 8192) * 256 + threadIdx.x;
    const size_t base = f * 8;
    const float4 a = *(const float4*)(w2 + base);
    const float4 b = *(const float4*)(w2 + base + 4);
    bf16x8 o;
    o[0] = (bf16)a.x; o[1] = (bf16)a.y; o[2] = (bf16)a.z; o[3] = (bf16)a.w;
    o[4] = (bf16)b.x; o[5] = (bf16)b.y; o[6] = (bf16)b.z; o[7] = (bf16)b.w;
    *(bf16x8*)(w2b + base) = o;
  }
}

// ====== v3 GEMMs: 64(M)x128(N), BK=64, DOUBLE-BUFFERED LDS ==================
// One barrier per k-iter; prefetch distance = 1 iter so the barrier's
// vmcnt(0) drain waits on loads issued a full compute-phase earlier.
// LDS per buffer: A 4096 elem (2 sub-k x 64rows x 32), B 8192 elem
// (2 sub-k x 128rows x 32). 2 buffers = 48 KB -> 3 blocks/CU.

// ------ Kernel 3 v3: grouped GEMM1 + SwiGLU ----------------------------------
__global__ __launch_bounds__(256) void k_gemm1v3(
    const bf16* __restrict__ tN, const bf16* __restrict__ w1b,
    const float* __restrict__ b1, const int* __restrict__ cnt,
    const int* __restrict__ segOff, const int* __restrict__ rowTok,
    bf16* __restrict__ sBuf)
{
  const int e = blockIdx.z, mt = blockIdx.y, nt = blockIdx.x;
  const int rows = cnt[e];
  if (mt * 64 >= rows) return;
  const int soff = segOff[e];
  __shared__ __align__(16) bf16 SM[2 * 12288];   // 48 KB
  const int tid = threadIdx.x;
  const int wid = tid >> 6, lane = tid & 63;
  const int quad = lane >> 4, l16 = lane & 15;
  const int wm = wid & 1, wn = wid >> 1;

  const int r0 = wid * 16 + (lane >> 2);     // [0,64)
  const int colE = (lane & 3) * 8;
  const int mA = min(mt * 64 + r0, rows - 1);
  const char* gA  = (const char*)(tN + (size_t)rowTok[soff + mA] * HD + colE);
  const int n0 = nt * 128;
  const char* gB0 = (const char*)(w1b + ((size_t)e * IDIM + n0 + r0) * HD + colE);
  const char* gB1 = (const char*)(w1b + ((size_t)e * IDIM + n0 + 64 + r0) * HD + colE);

  // stage tile 0 -> buffer 0
  {
    bf16* dA  = SM + wid * 512;
    bf16* dB0 = SM + 4096 + wid * 512;
    bf16* dB1 = SM + 6144 + wid * 512;
    async_copy16(gA, dA);        async_copy16(gA + 64, dA + 2048);
    async_copy16(gB0, dB0);      async_copy16(gB0 + 64, dB0 + 4096);
    async_copy16(gB1, dB1);      async_copy16(gB1 + 64, dB1 + 4096);
    gA += 128; gB0 += 128; gB1 += 128;
  }

  const f32x4 zero = {0.f, 0.f, 0.f, 0.f};
  f32x4 acc[2][4];
  #pragma unroll
  for (int i = 0; i < 2; ++i)
    #pragma unroll
    for (int j = 0; j < 4; ++j) acc[i][j] = zero;

  for (int kt = 0; kt < 16; ++kt) {
    __syncthreads();   // drains tile-kt copies (issued one iter ago)
    if (kt < 15) {
      const int nb = (kt + 1) & 1;
      bf16* dA  = SM + nb * 12288 + wid * 512;
      bf16* dB0 = SM + nb * 12288 + 4096 + wid * 512;
      bf16* dB1 = SM + nb * 12288 + 6144 + wid * 512;
      async_copy16(gA, dA);        async_copy16(gA + 64, dA + 2048);
      async_copy16(gB0, dB0);      async_copy16(gB0 + 64, dB0 + 4096);
      async_copy16(gB1, dB1);      async_copy16(gB1 + 64, dB1 + 4096);
      gA += 128; gB0 += 128; gB1 += 128;
    }
    const bf16* cb = SM + (kt & 1) * 12288;
    #pragma unroll
    for (int s = 0; s < 2; ++s) {
      const bf16x8 a0 = *(const bf16x8*)(cb + s * 2048 + (wm * 32 + l16) * 32 + quad * 8);
      const bf16x8 a1 = *(const bf16x8*)(cb + s * 2048 + (wm * 32 + 16 + l16) * 32 + quad * 8);
      #pragma unroll
      for (int j = 0; j < 4; ++j) {
        const bf16x8 bv = *(const bf16x8*)(cb + 4096 + s * 4096 + (wn * 64 + j * 16 + l16) * 32 + quad * 8);
        acc[0][j] = __builtin_amdgcn_mfma_f32_16x16x32_bf16(a0, bv, acc[0][j], 0, 0, 0);
        acc[1][j] = __builtin_amdgcn_mfma_f32_16x16x32_bf16(a1, bv, acc[1][j], 0, 0, 0);
      }
    }
  }

  const int mbase = mt * 64 + wm * 32;
  #pragma unroll
  for (int j = 0; j < 4; ++j) {
    const int ncol = n0 + wn * 64 + j * 16 + l16;
    const float bias = b1[(size_t)e * I2 + 2 * ncol];
    #pragma unroll
    for (int i = 0; i < 2; ++i) {
      #pragma unroll
      for (int rg = 0; rg < 4; ++rg) {
        const int gm = mbase + i * 16 + quad * 4 + rg;
        if (gm < rows) {
          const float h  = acc[i][j][rg] + bias;
          const float xg = fminf(h, 7.0f);
          const float s  = xg * (1.0f / (1.0f + __expf(-1.702f * xg))) * 8.0f;
          sBuf[((size_t)soff + gm) * IDIM + ncol] = (bf16)s;
        }
      }
    }
  }
}

// ------ Kernel 4 v3: grouped GEMM2; epilogue = yBuf stores or atomic ---------
template <bool USEY>
__global__ __launch_bounds__(256) void k_gemm2v3(
    const bf16* __restrict__ sBuf, const bf16* __restrict__ w2b,
    const float* __restrict__ b2, const int* __restrict__ cnt,
    const int* __restrict__ segOff, const int* __restrict__ rowTok,
    const float* __restrict__ rowW, bf16* __restrict__ yBuf,
    float* __restrict__ out)
{
  const int e = blockIdx.z, mt = blockIdx.y, nt = blockIdx.x;
  const int rows = cnt[e];
  if (mt * 64 >= rows) return;
  const int soff = segOff[e];
  __shared__ __align__(16) bf16 SM[2 * 12288];   // 48 KB
  const int tid = threadIdx.x;
  const int wid = tid >> 6, lane = tid & 63;
  const int quad = lane >> 4, l16 = lane & 15;
  const int wm = wid & 1, wn = wid >> 1;

  const int r0 = wid * 16 + (lane >> 2);
  const int colE = (lane & 3) * 8;
  const int mA = min(mt * 64 + r0, rows - 1);
  const char* gA  = (const char*)(sBuf + ((size_t)soff + mA) * IDIM + colE);
  const int n0 = nt * 128;
  const char* gB0 = (const char*)(w2b + ((size_t)e * HD + n0 + r0) * IDIM + colE);
  const char* gB1 = (const char*)(w2b + ((size_t)e * HD + n0 + 64 + r0) * IDIM + colE);

  {
    bf16* dA  = SM + wid * 512;
    bf16* dB0 = SM + 4096 + wid * 512;
    bf16* dB1 = SM + 6144 + wid * 512;
    async_copy16(gA, dA);        async_copy16(gA + 64, dA + 2048);
    async_copy16(gB0, dB0);      async_copy16(gB0 + 64, dB0 + 4096);
    async_copy16(gB1, dB1);      async_copy16(gB1 + 64, dB1 + 4096);
    gA += 128; gB0 += 128; gB1 += 128;
  }

  const f32x4 zero = {0.f, 0.f, 0.f, 0.f};
  f32x4 acc[2][4];
  #pragma unroll
  for (int i = 0; i < 2; ++i)
    #pragma unroll
    for (int j = 0; j < 4; ++j) acc[i][j] = zero;

  for (int kt = 0; kt < 16; ++kt) {
    __syncthreads();
    if (kt < 15) {
      const int nb = (kt + 1) & 1;
      bf16* dA  = SM + nb * 12288 + wid * 512;
      bf16* dB0 = SM + nb * 12288 + 4096 + wid * 512;
      bf16* dB1 = SM + nb * 12288 + 6144 + wid * 512;
      async_copy16(gA, dA);        async_copy16(gA + 64, dA + 2048);
      async_copy16(gB0, dB0);      async_copy16(gB0 + 64, dB0 + 4096);
      async_copy16(gB1, dB1);      async_copy16(gB1 + 64, dB1 + 4096);
      gA += 128; gB0 += 128; gB1 += 128;
    }
    const bf16* cb = SM + (kt & 1) * 12288;
    #pragma unroll
    for (int s = 0; s < 2; ++s) {
      const bf16x8 a0 = *(const bf16x8*)(cb + s * 2048 + (wm * 32 + l16) * 32 + quad * 8);
      const bf16x8 a1 = *(const bf16x8*)(cb + s * 2048 + (wm * 32 + 16 + l16) * 32 + quad * 8);
      #pragma unroll
      for (int j = 0; j < 4; ++j) {
        const bf16x8 bv = *(const bf16x8*)(cb + 4096 + s * 4096 + (wn * 64 + j * 16 + l16) * 32 + quad * 8);
        acc[0][j] = __builtin_amdgcn_mfma_f32_16x16x32_bf16(a0, bv, acc[0][j], 0, 0, 0);
        acc[1][j] = __builtin_amdgcn_mfma_f32_16x16x32_bf16(a1, bv, acc[1][j], 0, 0, 0);
      }
    }
  }

  const int mbase = mt * 64 + wm * 32;
  #pragma unroll
  for (int j = 0; j < 4; ++j) {
    const int ncol = n0 + wn * 64 + j * 16 + l16;
    const float bias = b2[(size_t)e * HD + ncol];
    #pragma unroll
    for (int i = 0; i < 2; ++i) {
      #pragma unroll
      for (int rg = 0; rg < 4; ++rg) {
        const int gm = mbase + i * 16 + quad * 4 + rg;
        if (gm < rows) {
          if constexpr (USEY) {
            yBuf[((size_t)soff + gm) * HD + ncol] = (bf16)(acc[i][j][rg] + bias);
          } else {
            atomicAdd(out + (size_t)rowTok[soff + gm] * HD + ncol,
                      rowW[soff + gm] * (acc[i][j][rg] + bias));
          }
        }
      }
    }
  }
}

// ------ Kernel 5: finalize  out = x + sum_k w_k * y_k ------------------------
__global__ __launch_bounds__(256) void k_finalize(
    const float* __restrict__ x, const bf16* __restrict__ yBuf,
    const int* __restrict__ rowOf, const float* __restrict__ wts,
    float* __restrict__ out)
{
  const int tok = blockIdx.x;
  const int tid = threadIdx.x;
  const int r0 = rowOf[tok * 4 + 0], r1 = rowOf[tok * 4 + 1];
  const int r2 = rowOf[tok * 4 + 2], r3 = rowOf[tok * 4 + 3];
  const float w0 = wts[tok * 4 + 0], w1 = wts[tok * 4 + 1];
  const float w2 = wts[tok * 4 + 2], w3 = wts[tok * 4 + 3];
  const int col = tid * 4;
  float4 o = *(const float4*)(x + (size_t)tok * HD + col);
  const bf16x4 y0 = *(const bf16x4*)(yBuf + (size_t)r0 * HD + col);
  const bf16x4 y1 = *(const bf16x4*)(yBuf + (size_t)r1 * HD + col);
  const bf16x4 y2 = *(const bf16x4*)(yBuf + (size_t)r2 * HD + col);
  const bf16x4 y3 = *(const bf16x4*)(yBuf + (size_t)r3 * HD + col);
  o.x += w0 * (float)y0[0] + w1 * (float)y1[0] + w2 * (float)y2[0] + w3 * (float)y3[0];
  o.y += w0 * (float)y0[1] + w1 * (float)y1[1] + w2 * (float)y2[1] + w3 * (float)y3[1];
  o.z += w0 * (float)y0[2] + w1 * (float)y1[2] + w2 * (float)y2[2] + w3 * (float)y3[2];
  o.w += w0 * (float)y0[3] + w1 * (float)y1[3] + w2 * (float)y2[3] + w3 * (float)y3[3];
  *(float4*)(out + (size_t)tok * HD + col) = o;
}

// ====== fallback GEMMs (128x128, BK=32, fp32 B in-loop convert) ==============
__global__ __launch_bounds__(256) void k_gemm1_fb(
    const bf16* __restrict__ tN, const float* __restrict__ w1,
    const float* __restrict__ b1, const int* __restrict__ cnt,
    const int* __restrict__ segOff, const int* __restrict__ rowTok,
    bf16* __restrict__ sBuf)
{
  const int e = blockIdx.z, mt = blockIdx.y, nt = blockIdx.x;
  const int rows = cnt[e];
  if (mt * 128 >= rows) return;
  const int soff = segOff[e];
  __shared__ __align__(16) bf16 Asm[128 * 32];
  __shared__ __align__(16) bf16 Bsm[128 * 32];
  const int tid = threadIdx.x;
  const int wid = tid >> 6, lane = tid & 63;
  const int quad = lane >> 4, l16 = lane & 15;
  const int wm = wid & 1, wn = wid >> 1;
  const int r0 = wid * 16 + (lane >> 2);
  const int r1 = 64 + r0;
  const int colE = (lane & 3) * 8;
  const int m0 = min(mt * 128 + r0, rows - 1);
  const int m1 = min(mt * 128 + r1, rows - 1);
  const char* gA0 = (const char*)(tN + (size_t)rowTok[soff + m0] * HD + colE);
  const char* gA1 = (const char*)(tN + (size_t)rowTok[soff + m1] * HD + colE);
  bf16* lA0 = Asm + wid * 512;
  bf16* lA1 = Asm + 2048 + wid * 512;
  const int brow = tid >> 3;
  const int bkk  = (tid & 7) * 4;
  const int n0 = nt * 128;
  const float* gB = w1 + (size_t)e * I2 * HD + (size_t)(2 * (n0 + brow)) * HD + bkk;

  const f32x4 zero = {0.f, 0.f, 0.f, 0.f};
  f32x4 acc[4][4];
  #pragma unroll
  for (int i = 0; i < 4; ++i)
    #pragma unroll
    for (int j = 0; j < 4; ++j) acc[i][j] = zero;

  for (int kt = 0; kt < 32; ++kt) {
    async_copy16(gA0, lA0);
    async_copy16(gA1, lA1);
    gA0 += 64; gA1 += 64;
    #pragma unroll
    for (int q = 0; q < 4; ++q) {
      const float4 v = *(const float4*)(gB + (size_t)q * 64 * HD);
      bf16x4 c;
      c[0] = (bf16)v.x; c[1] = (bf16)v.y; c[2] = (bf16)v.z; c[3] = (bf16)v.w;
      *(bf16x4*)(Bsm + (q * 32 + brow) * 32 + bkk) = c;
    }
    gB += 32;
    __syncthreads();
    bf16x8 av[4], bv[4];
    #pragma unroll
    for (int i = 0; i < 4; ++i)
      av[i] = *(const bf16x8*)(Asm + (wm * 64 + i * 16 + l16) * 32 + quad * 8);
    #pragma unroll
    for (int j = 0; j < 4; ++j)
      bv[j] = *(const bf16x8*)(Bsm + (wn * 64 + j * 16 + l16) * 32 + quad * 8);
    #pragma unroll
    for (int i = 0; i < 4; ++i)
      #pragma unroll
      for (int j = 0; j < 4; ++j)
        acc[i][j] = __builtin_amdgcn_mfma_f32_16x16x32_bf16(av[i], bv[j], acc[i][j], 0, 0, 0);
    __syncthreads();
  }
  const int mbase = mt * 128 + wm * 64;
  #pragma unroll
  for (int j = 0; j < 4; ++j) {
    const int ncol = n0 + wn * 64 + j * 16 + l16;
    const float bias = b1[(size_t)e * I2 + 2 * ncol];
    #pragma unroll
    for (int i = 0; i < 4; ++i) {
      #pragma unroll
      for (int rg = 0; rg < 4; ++rg) {
        const int gm = mbase + i * 16 + quad * 4 + rg;
        if (gm < rows) {
          const float h  = acc[i][j][rg] + bias;
          const float xg = fminf(h, 7.0f);
          const float s  = xg * (1.0f / (1.0f + __expf(-1.702f * xg))) * 8.0f;
          sBuf[((size_t)soff + gm) * IDIM + ncol] = (bf16)s;
        }
      }
    }
  }
}

__global__ __launch_bounds__(256) void k_gemm2_fb(
    const bf16* __restrict__ sBuf, const float* __restrict__ w2,
    const float* __restrict__ b2, const int* __restrict__ cnt,
    const int* __restrict__ segOff, const int* __restrict__ rowTok,
    const float* __restrict__ rowW, float* __restrict__ out)
{
  const int e = blockIdx.z, mt = blockIdx.y, nt = blockIdx.x;
  const int rows = cnt[e];
  if (mt * 128 >= rows) return;
  const int soff = segOff[e];
  __shared__ __align__(16) bf16 Asm[128 * 32];
  __shared__ __align__(16) bf16 Bsm[128 * 32];
  const int tid = threadIdx.x;
  const int wid = tid >> 6, lane = tid & 63;
  const int quad = lane >> 4, l16 = lane & 15;
  const int wm = wid & 1, wn = wid >> 1;
  const int r0 = wid * 16 + (lane >> 2);
  const int r1 = 64 + r0;
  const int colE = (lane & 3) * 8;
  const int m0 = min(mt * 128 + r0, rows - 1);
  const int m1 = min(mt * 128 + r1, rows - 1);
  const char* gA0 = (const char*)(sBuf + ((size_t)soff + m0) * IDIM + colE);
  const char* gA1 = (const char*)(sBuf + ((size_t)soff + m1) * IDIM + colE);
  bf16* lA0 = Asm + wid * 512;
  bf16* lA1 = Asm + 2048 + wid * 512;
  const int brow = tid >> 3;
  const int bkk  = (tid & 7) * 4;
  const int n0 = nt * 128;
  const float* gB = w2 + (size_t)e * HD * IDIM + (size_t)(n0 + brow) * IDIM + bkk;

  const f32x4 zero = {0.f, 0.f, 0.f, 0.f};
  f32x4 acc[4][4];
  #pragma unroll
  for (int i = 0; i < 4; ++i)
    #pragma unroll
    for (int j = 0; j < 4; ++j) acc[i][j] = zero;

  for (int kt = 0; kt < 32; ++kt) {
    async_copy16(gA0, lA0);
    async_copy16(gA1, lA1);
    gA0 += 64; gA1 += 64;
    #pragma unroll
    for (int q = 0; q < 4; ++q) {
      const float4 v = *(const float4*)(gB + (size_t)q * 32 * IDIM);
      bf16x4 c;
      c[0] = (bf16)v.x; c[1] = (bf16)v.y; c[2] = (bf16)v.z; c[3] = (bf16)v.w;
      *(bf16x4*)(Bsm + (q * 32 + brow) * 32 + bkk) = c;
    }
    gB += 32;
    __syncthreads();
    bf16x8 av[4], bv[4];
    #pragma unroll
    for (int i = 0; i < 4; ++i)
      av[i] = *(const bf16x8*)(Asm + (wm * 64 + i * 16 + l16) * 32 + quad * 8);
    #pragma unroll
    for (int j = 0; j < 4; ++j)
      bv[j] = *(const bf16x8*)(Bsm + (wn * 64 + j * 16 + l16) * 32 + quad * 8);
    #pragma unroll
    for (int i = 0; i < 4; ++i)
      #pragma unroll
      for (int j = 0; j < 4; ++j)
        acc[i][j] = __builtin_amdgcn_mfma_f32_16x16x32_bf16(av[i], bv[j], acc[i][j], 0, 0, 0);
    __syncthreads();
  }
  const int mbase = mt * 128 + wm * 64;
  #pragma unroll
  for (int j = 0; j < 4; ++j) {
    const int ncol = n0 + wn * 64 + j * 16 + l16;
    const float bias = b2[(size_t)e * HD + ncol];
    #pragma unroll
    for (int i = 0; i < 4; ++i) {
      #pragma unroll
      for (int rg = 0; rg < 4; ++rg) {
        const int gm = mbase + i * 16 + quad * 4 + rg;
        if (gm < rows) {
          atomicAdd(out + (size_t)rowTok[soff + gm] * HD + ncol,
                    rowW[soff + gm] * (acc[i][j][rg] + bias));
        }
      }
    }
  }
}

// ---------------- launch -----------------------------------------------------
extern "C" void kernel_launch(void* const* d_in, const int* in_sizes, int n_in,
                              void* d_out, int out_size, void* d_ws, size_t ws_size,
                              hipStream_t stream) {
  const float* x      = (const float*)d_in[0];
  const float* scale  = (const float*)d_in[1];
  const float* gate_w = (const float*)d_in[2];
  const float* gate_b = (const float*)d_in[3];
  const float* w1     = (const float*)d_in[4];
  const float* b1     = (const float*)d_in[5];
  const float* w2     = (const float*)d_in[6];
  const float* b2     = (const float*)d_in[7];
  float* out = (float*)d_out;

  // base workspace (~21.2 MB)
  char* p = (char*)d_ws;
  bf16* tN   = (bf16*)p;  p += (size_t)TKN * HD * 2;        // 4 MB
  bf16* sBuf = (bf16*)p;  p += (size_t)NROW * IDIM * 2;     // 16 MB
  int*   eids   = (int*)p;   p += (size_t)NROW * 4;
  float* wts    = (float*)p; p += (size_t)NROW * 4;
  int*   rowTok = (int*)p;   p += (size_t)NROW * 4;
  float* rowW   = (float*)p; p += (size_t)NROW * 4;
  int*   rowOf  = (int*)p;   p += (size_t)NROW * 4;
  int*   cntg   = (int*)p;   p += 256;
  int*   segg   = (int*)p;   p += 256;
  const size_t base_need = (size_t)(p - (char*)d_ws);
  const size_t WSZ = (size_t)NEXP * IDIM * HD * 2;          // 33.55 MB each
  bf16* w2b  = (bf16*)p;
  bf16* w1b  = (bf16*)(p + WSZ);
  bf16* yBuf = (bf16*)(p + 2 * WSZ);                        // 16 MB
  const bool prep  = ws_size >= base_need + 2 * WSZ;
  const bool useY  = prep &&
                     (ws_size >= base_need + 2 * WSZ + (size_t)NROW * HD * 2);

  k_norm_gate<<<TKN, 256, 0, stream>>>(x, scale, gate_w, gate_b, out, tN, eids, wts);
  k_route<<<1, 256, 0, stream>>>(eids, wts, cntg, segg, rowTok, rowW, rowOf);

  if (prep) {
    k_cvt_all<<<16384, 256, 0, stream>>>(w1, w2, w1b, w2b);
    k_gemm1v3<<<dim3(8, 32, NEXP), 256, 0, stream>>>(tN, w1b, b1, cntg, segg, rowTok, sBuf);
    if (useY) {
      k_gemm2v3<true><<<dim3(8, 32, NEXP), 256, 0, stream>>>(sBuf, w2b, b2, cntg, segg,
                                                             rowTok, rowW, yBuf, out);
      k_finalize<<<TKN, 256, 0, stream>>>(x, yBuf, rowOf, wts, out);
    } else {
      k_gemm2v3<false><<<dim3(8, 32, NEXP), 256, 0, stream>>>(sBuf, w2b, b2, cntg, segg,
                                                              rowTok, rowW, yBuf, out);
    }
  } else {
    k_gemm1_fb<<<dim3(8, 16, NEXP), 256, 0, stream>>>(tN, w1, b1, cntg, segg, rowTok, sBuf);
    k_gemm2_fb<<<dim3(8, 16, NEXP), 256, 0, stream>>>(sBuf, w2, b2, cntg, segg, rowTok, rowW, out);
  }
}